// Round 10
// baseline (178.576 us; speedup 1.0000x reference)
//
#include <hip/hip_runtime.h>
#include <hip/hip_cooperative_groups.h>
#include <cstdint>

#define NUM_CLASSES 80
#define NPRED 8400
#define NBATCH 32
#define TOPK_N 1000
#define SORTN 16384
#define CONF_T 0.25f
#define NMS_T 0.45f
#define STRIDE 85

#define ROWS_PB 128
#define FLOATS_PB (ROWS_PB * STRIDE)   // 10880
#define F4_PB (FLOATS_PB / 4)          // 2720
#define NTILES (NBATCH * NPRED / ROWS_PB) // 2100
#define REC_F 8                        // floats per record (padded to 32B)
#define MPAD 1026                      // lmask row stride in words (bank skew)
#define CBUF_CAP 2048

// mega/fused LDS pool layout (64-bit words):
//   decode phase: s0 [0,5440) | s1 [5440,10880) | h2 (u32 x2048) [10880,11904)
//   select phase: k_lds [0,8400) | hist (u32 x4096) [8400,10448) | sortbuf [10448,11472)
//                 | cbuf [11472,13520)
//   mask phase:   lmask 16xMPAD [0,16416) | x1o..y2o [16416,18416) | clsbm [18416,19696)
#define POOLW 19696                    // 157,568 bytes

__device__ __forceinline__ uint32_t f32_sortable(float f) {
    uint32_t u = __float_as_uint(f);
    return u ^ ((u >> 31) ? 0xFFFFFFFFu : 0x80000000u);
}

__device__ __forceinline__ uint64_t shfl_xor_u64(uint64_t x, int m) {
    uint32_t lo = (uint32_t)x, hi = (uint32_t)(x >> 32);
    lo = (uint32_t)__shfl_xor((int)lo, m);
    hi = (uint32_t)__shfl_xor((int)hi, m);
    return ((uint64_t)hi << 32) | lo;
}

// 46-bit key: (sortable(masked_score) << 14) | (16383 - e).
__device__ __forceinline__ uint64_t decode_row(const float* p, int e,
                                               float4* rec0, float4* rec1) {
    float cx = p[0], cy = p[1], w = p[2], h = p[3], obj = p[4];
    float best = p[5]; int bc = 0;
    #pragma unroll
    for (int c = 1; c < NUM_CLASSES; ++c) {
        float v = p[5 + c];
        if (v > best) { best = v; bc = c; }        // first-max wins, like jnp.argmax
    }
    float w2 = __fmul_rn(w, 0.5f), h2 = __fmul_rn(h, 0.5f);
    float score = __fmul_rn(obj, best);
    float masked = (score >= CONF_T) ? score : -1.0f;
    *rec0 = make_float4(__fsub_rn(cx, w2), __fsub_rn(cy, h2),
                        __fadd_rn(cx, w2), __fadd_rn(cy, h2));
    *rec1 = make_float4(score, (float)bc, 0.0f, 0.0f);
    return ((uint64_t)f32_sortable(masked) << 14) | (uint32_t)(16383 - e);
}

// ================= cooperative mega-kernel =================
// Phase A (256 blocks): decode, double-buffered staging; per-tile LDS hist of
// pass-1 bins (key>>36, 1024 bins) flushed to hist_g[batch][1024] via atomics.
// grid.sync. Phase B (blocks 0..31): select (pass 1 from hist_g; passes 2-4
// over the compacted pass-1-bin keys), bitonic, mask build, greedy scan, output.
__global__ __launch_bounds__(1024) void mega_kernel(const float* __restrict__ pred,
                                                    uint64_t* __restrict__ keys,
                                                    float* __restrict__ recs,
                                                    uint32_t* __restrict__ hist_g,
                                                    float* __restrict__ dets,
                                                    float* __restrict__ keep_out) {
    __shared__ uint64_t pool[POOLW];
    __shared__ uint64_t removed_w[16];
    __shared__ uint32_t wtot[16];
    __shared__ uint32_t sh_rem, sh_cnt, sh_ccnt;
    __shared__ uint64_t sh_prefix;

    const int tid = threadIdx.x;
    const int lane = tid & 63, wid = tid >> 6;

    // ---------------- phase A: decode + pass-1 partial hists ----------------
    {
        float* scur = (float*)pool;                // 5440 words
        float* snxt = (float*)(pool + 5440);
        uint32_t* h2 = (uint32_t*)(pool + 10880); // 2048 u32
        const bool has2 = (tid + 2048) < F4_PB;

        int t = blockIdx.x;
        if (t < NTILES) {                          // prologue: tile t -> scur
            const float4* g4 = (const float4*)pred + (size_t)t * F4_PB;
            float4* s4 = (float4*)scur;
            for (int i = tid; i < F4_PB; i += 1024) s4[i] = g4[i];
        }
        for (int i = tid; i < 2048; i += 1024) h2[i] = 0;
        __syncthreads();

        while (t < NTILES) {
            int tn = t + (int)gridDim.x;
            float4 rv0, rv1, rv2;
            if (tn < NTILES) {                     // issue next-tile loads early
                const float4* g4 = (const float4*)pred + (size_t)tn * F4_PB;
                rv0 = g4[tid]; rv1 = g4[tid + 1024];
                if (has2) rv2 = g4[tid + 2048];
            }
            const int r0r = t * ROWS_PB;
            const int batchA = r0r / NPRED, batchB = (r0r + ROWS_PB - 1) / NPRED;
            if (tid < ROWS_PB) {
                int r = r0r + tid;
                int batch = r / NPRED;
                int e = r - batch * NPRED;
                float4 rc0, rc1;
                uint64_t key = decode_row(scur + tid * STRIDE, e, &rc0, &rc1);
                keys[r] = key;
                float4* rp = (float4*)(recs + (size_t)r * REC_F);
                rp[0] = rc0; rp[1] = rc1;
                int sel = (batch == batchA) ? 0 : 1;
                atomicAdd(&h2[(sel << 10) + (uint32_t)(key >> 36)], 1u);
            }
            __syncthreads();
            if (tn < NTILES) {                     // write prefetched tile
                float4* s4 = (float4*)snxt;
                s4[tid] = rv0; s4[tid + 1024] = rv1;
                if (has2) s4[tid + 2048] = rv2;
            }
            for (int i = tid; i < 2048; i += 1024) {
                uint32_t h = h2[i];
                if (h) {
                    h2[i] = 0;
                    int bt = (i < 1024) ? batchA : batchB;
                    atomicAdd(&hist_g[(bt << 10) + (i & 1023)], h);
                }
            }
            __syncthreads();
            float* tmp = scur; scur = snxt; snxt = tmp;
            t = tn;
        }
    }
    __threadfence();
    cooperative_groups::this_grid().sync();
    if (blockIdx.x >= NBATCH) return;

    // ---------------- phase B: per-batch select + NMS ----------------
    const int b = blockIdx.x;
    uint64_t* k_lds = pool;                        // [0, 8400)
    uint32_t* hist = (uint32_t*)(pool + NPRED);    // 4096 u32
    uint64_t* sortbuf = pool + 10448;              // 1024
    uint64_t* cbuf = pool + 11472;                 // 2048

    if (tid == 0) { sh_rem = TOPK_N; sh_prefix = 0; sh_cnt = 0; sh_ccnt = 0; }
    sortbuf[tid] = 0;                              // pads sink
    for (int e0 = 0; e0 < NPRED; e0 += 1024) {
        int e = e0 + tid;
        if (e < NPRED) k_lds[e] = keys[(size_t)b * NPRED + e];
    }
    uint32_t hmine = hist_g[(b << 10) + tid];      // my pass-1 bin count
    __syncthreads();

    // pass 1: suffix scan over 1024 bins (1 bin/thread), from precomputed hist
    {
        uint32_t v = hmine;
        #pragma unroll
        for (int off = 1; off < 64; off <<= 1) {
            uint32_t u = __shfl_down(v, off);
            if (lane + off < 64) v += u;
        }
        if (lane == 0) wtot[wid] = v;
        __syncthreads();
        uint32_t carry = 0;
        for (int w = wid + 1; w < 16; ++w) carry += wtot[w];
        uint32_t S0 = v + carry;                   // count of keys in bins >= tid
        if (S0 >= TOPK_N && S0 - hmine < TOPK_N) { // unique crossing thread
            sh_prefix = (uint64_t)(uint32_t)tid << 36;
            sh_rem = TOPK_N - (S0 - hmine);
        }
        __syncthreads();
    }

    // compact keys in the chosen pass-1 bin (exactness fallback if > CBUF_CAP)
    const uint32_t bin1 = (uint32_t)(sh_prefix >> 36);
    for (int e0 = 0; e0 < NPRED; e0 += 1024) {
        int e = e0 + tid;
        uint64_t k = (e < NPRED) ? k_lds[e] : 0;
        bool pr = (e < NPRED) && ((uint32_t)(k >> 36) == bin1);
        uint64_t bal = __ballot(pr);
        uint32_t base = 0;
        if (lane == 0 && bal) base = atomicAdd(&sh_ccnt, (uint32_t)__popcll(bal));
        base = __shfl(base, 0);
        if (pr) {
            uint32_t pos = base + (uint32_t)__popcll(bal & ((1ull << lane) - 1ull));
            if (pos < CBUF_CAP) cbuf[pos] = k;
        }
    }
    __syncthreads();
    const uint32_t ccnt = sh_ccnt;
    const bool use_c = (ccnt <= CBUF_CAP);
    const uint64_t* src = use_c ? cbuf : k_lds;
    const int srcN = use_c ? (int)ccnt : NPRED;

    // passes 2-4 over the compacted set (~400 keys)
    for (int shift = 24; shift >= 0; shift -= 12) {
        #pragma unroll
        for (int i = 0; i < 4; ++i) hist[tid * 4 + i] = 0;
        __syncthreads();
        const uint64_t himask = ~0ull << (shift + 12);
        const uint64_t pref = sh_prefix;
        const uint32_t rem = sh_rem;
        for (int e = tid; e < srcN; e += 1024) {
            uint64_t k = src[e];
            if ((k & himask) == (pref & himask))
                atomicAdd(&hist[(uint32_t)(k >> shift) & 4095u], 1u);
        }
        __syncthreads();
        uint32_t h0 = hist[tid * 4 + 0], h1 = hist[tid * 4 + 1];
        uint32_t h2 = hist[tid * 4 + 2], h3 = hist[tid * 4 + 3];
        uint32_t s4 = h0 + h1 + h2 + h3;
        uint32_t v = s4;
        #pragma unroll
        for (int off = 1; off < 64; off <<= 1) {
            uint32_t u = __shfl_down(v, off);
            if (lane + off < 64) v += u;
        }
        if (lane == 0) wtot[wid] = v;
        __syncthreads();
        uint32_t carry = 0;
        for (int w = wid + 1; w < 16; ++w) carry += wtot[w];
        uint32_t S0 = v + carry;
        uint32_t carry_after = S0 - s4;
        if (carry_after < rem && S0 >= rem) {
            uint32_t hh[4] = {h0, h1, h2, h3};
            uint32_t pre = 0, bestS = S0, besth = h0;
            int besti = 0;
            #pragma unroll
            for (int i = 0; i < 4; ++i) {
                uint32_t Si = S0 - pre;
                if (Si >= rem) { besti = i; bestS = Si; besth = hh[i]; }
                pre += hh[i];
            }
            sh_prefix = pref | ((uint64_t)(uint32_t)(tid * 4 + besti) << shift);
            sh_rem = rem - (bestS - besth);
        }
        __syncthreads();
    }

    // winner compaction (exactly 1000 keys >= T; keys unique)
    const uint64_t T = sh_prefix;
    for (int e0 = 0; e0 < NPRED; e0 += 1024) {
        int e = e0 + tid;
        uint64_t k = (e < NPRED) ? k_lds[e] : 0;
        bool pr = (e < NPRED) && (k >= T);
        uint64_t bal = __ballot(pr);
        uint32_t base = 0;
        if (lane == 0 && bal) base = atomicAdd(&sh_cnt, (uint32_t)__popcll(bal));
        base = __shfl(base, 0);
        if (pr) {
            uint32_t pos = base + (uint32_t)__popcll(bal & ((1ull << lane) - 1ull));
            if (pos < 1024) sortbuf[pos] = k;
        }
    }
    __syncthreads();

    // bitonic sort descending: LDS for j>=64, register shfl_xor inside wave
    uint64_t v64 = sortbuf[tid];
    for (unsigned k = 2; k <= 1024; k <<= 1) {
        for (unsigned j = k >> 1; j > 0; j >>= 1) {
            uint64_t o;
            if (j >= 64) {
                __syncthreads();
                sortbuf[tid] = v64;
                __syncthreads();
                o = sortbuf[tid ^ j];
            } else {
                o = shfl_xor_u64(v64, (int)j);
            }
            bool lower = (tid & j) == 0;
            bool desc = (tid & k) == 0;
            v64 = (lower == desc) ? (v64 > o ? v64 : o) : (v64 < o ? v64 : o);
        }
    }

    // ---- gather + class bitmaps + in-LDS mask ----
    uint64_t* lmask = pool;                        // [0, 16416)
    float* x1o = (float*)(pool + 16416);
    float* y1o = x1o + TOPK_N;
    float* x2o = y1o + TOPK_N;
    float* y2o = x2o + TOPK_N;
    uint64_t* clsbm = pool + 18416;                // 16 x 80

    float4 r0 = make_float4(0, 0, 0, 0), r1 = make_float4(0, 0, 0, 0);
    bool invalid = false;
    if (tid < TOPK_N) {
        int e = 16383 - (int)((uint32_t)v64 & 16383u);
        const float4* rp = (const float4*)(recs + ((size_t)b * NPRED + e) * REC_F);
        r0 = rp[0]; r1 = rp[1];
        invalid = (r1.x < CONF_T);
    }
    {
        uint64_t bal = __ballot(invalid);
        if ((tid & 63) == 0) removed_w[tid >> 6] = bal;
    }
    for (int i = tid; i < 16 * NUM_CLASSES; i += 1024) clsbm[i] = 0;
    __syncthreads();                               // select-era LDS reads retired

    float ax1 = 0, ay1 = 0, ax2 = 0, ay2 = 0, areai = 0;
    int mycls = 0;
    if (tid < TOPK_N) {
        float offv = __fmul_rn(r1.y, 10.0f);       // exact: class*10 <= 790
        ax1 = __fadd_rn(r0.x, offv); ay1 = __fadd_rn(r0.y, offv);
        ax2 = __fadd_rn(r0.z, offv); ay2 = __fadd_rn(r0.w, offv);
        areai = __fmul_rn(__fsub_rn(ax2, ax1), __fsub_rn(ay2, ay1));
        mycls = (int)r1.y;
        x1o[tid] = ax1; y1o[tid] = ay1; x2o[tid] = ax2; y2o[tid] = ay2;
        atomicOr(&clsbm[(tid >> 6) * NUM_CLASSES + mycls], 1ull << (tid & 63));
    }
    __syncthreads();

    const int myw = tid >> 6;
    if (tid < TOPK_N) {
        for (int w = 0; w < 16; ++w) {
            uint64_t bits = 0;
            if (w >= myw) {
                uint64_t bm = clsbm[w * NUM_CLASSES + mycls];
                if (w == myw) bm &= ~((2ull << (tid & 63)) - 1ull);  // j > tid only
                while (bm) {
                    int bb = __builtin_ctzll(bm);
                    bm &= bm - 1;
                    int j = w * 64 + bb;
                    float jx1 = x1o[j], jy1 = y1o[j], jx2 = x2o[j], jy2 = y2o[j];
                    float areaj = __fmul_rn(__fsub_rn(jx2, jx1), __fsub_rn(jy2, jy1));
                    float ix1 = fmaxf(ax1, jx1), iy1 = fmaxf(ay1, jy1);
                    float ix2 = fminf(ax2, jx2), iy2 = fminf(ay2, jy2);
                    float dx = fmaxf(__fsub_rn(ix2, ix1), 0.0f);
                    float dy = fmaxf(__fsub_rn(iy2, iy1), 0.0f);
                    float inter = __fmul_rn(dx, dy);
                    float uni = __fsub_rn(__fadd_rn(areai, areaj), inter);
                    float iou = __fdiv_rn(inter, fmaxf(uni, 1e-9f));
                    if (iou > NMS_T) bits |= (1ull << bb);
                }
            }
            lmask[w * MPAD + tid] = bits;
        }
    } else {
        #pragma unroll
        for (int w = 0; w < 16; ++w) lmask[w * MPAD + tid] = 0;  // phantom rows
    }
    __syncthreads();

    // ---- greedy scan (register preload, VALU chain) ----
    if (tid < 64) {
        const int l = tid & 15;
        uint64_t rem = (tid < 16) ? removed_w[tid] : 0;
        for (int W = 0; W < 16; ++W) {
            uint64_t cur = __shfl(rem, W);
            const int base = W * 64;
            #pragma unroll
            for (int sb = 0; sb < 64; sb += 16) {
                uint64_t mW[16], ml[16];
                #pragma unroll
                for (int q = 0; q < 16; ++q) {
                    int i = base + sb + q;
                    mW[q] = lmask[W * MPAD + i];
                    ml[q] = lmask[l * MPAD + i];
                }
                #pragma unroll
                for (int q = 0; q < 16; ++q) {
                    int bb = sb + q;
                    uint64_t sel = ((cur >> bb) & 1ull) ? 0ull : ~0ull;
                    cur |= (mW[q] & sel);
                    rem |= (ml[q] & sel);
                }
            }
        }
        if (tid < 16) removed_w[tid] = rem;
    }
    __syncthreads();

    if (tid < TOPK_N) {
        bool kept = ((removed_w[tid >> 6] >> (tid & 63)) & 1ull) == 0;
        float* dr = dets + ((size_t)b * TOPK_N + tid) * 6;
        if (kept) {
            dr[0] = r0.x; dr[1] = r0.y; dr[2] = r0.z; dr[3] = r0.w;
            dr[4] = r1.x; dr[5] = r1.y;
        } else {
            dr[0] = 0.0f; dr[1] = 0.0f; dr[2] = 0.0f;
            dr[3] = 0.0f; dr[4] = 0.0f; dr[5] = 0.0f;
        }
        keep_out[b * TOPK_N + tid] = kept ? 1.0f : 0.0f;
    }
}

// ================= fallback kernels (r9 path) =================

__global__ __launch_bounds__(256) void decode_kernel(const float* __restrict__ pred,
                                                     uint64_t* __restrict__ keys,
                                                     float* __restrict__ recs) {
    __shared__ float s[FLOATS_PB];
    const int blk = blockIdx.x;
    const int tid = threadIdx.x;
    const float4* g4 = (const float4*)pred + (size_t)blk * F4_PB;
    float4* s4 = (float4*)s;
    for (int i = tid; i < F4_PB; i += 256) s4[i] = g4[i];
    __syncthreads();
    if (tid < ROWS_PB) {
        int r = blk * ROWS_PB + tid;
        int e = r % NPRED;
        float4 rc0, rc1;
        uint64_t key = decode_row(s + tid * STRIDE, e, &rc0, &rc1);
        keys[r] = key;
        if (recs) {
            float4* rp = (float4*)(recs + (size_t)r * REC_F);
            rp[0] = rc0; rp[1] = rc1;
        }
    }
}

__global__ __launch_bounds__(1024) void fused_kernel(const uint64_t* __restrict__ keys,
                                                     const float* __restrict__ recs,
                                                     float* __restrict__ dets,
                                                     float* __restrict__ keep_out) {
    __shared__ uint64_t pool[POOLW];
    __shared__ uint64_t removed_w[16];
    __shared__ uint32_t wtot[16];
    __shared__ uint32_t sh_rem, sh_cnt, sh_inv;
    __shared__ uint64_t sh_prefix;

    const int b = blockIdx.x;
    const int tid = threadIdx.x;
    const int lane = tid & 63, wid = tid >> 6;
    const uint64_t INV_HI = (uint64_t)f32_sortable(-1.0f);

    uint64_t* k_lds = pool;
    uint32_t* hist = (uint32_t*)(pool + NPRED);
    uint64_t* sortbuf = pool + 10448;

    if (tid == 0) { sh_rem = TOPK_N; sh_prefix = 0; sh_cnt = 0; sh_inv = 0; }
    sortbuf[tid] = 0;
    __syncthreads();

    uint32_t invw = 0;
    for (int e0 = 0; e0 < NPRED; e0 += 1024) {
        int e = e0 + tid;
        uint64_t k = 0;
        if (e < NPRED) { k = keys[(size_t)b * NPRED + e]; k_lds[e] = k; }
        uint64_t bal = __ballot((e < NPRED) && ((k >> 14) == INV_HI));
        if (lane == 0) invw += (uint32_t)__popcll(bal);
    }
    if (lane == 0 && invw) atomicAdd(&sh_inv, invw);
    __syncthreads();

    for (int shift = 36; shift >= 0; shift -= 12) {
        #pragma unroll
        for (int i = 0; i < 4; ++i) hist[tid * 4 + i] = 0;
        __syncthreads();
        const uint64_t himask = (shift == 36) ? 0ull : (~0ull << (shift + 12));
        const uint64_t pref = sh_prefix;
        const uint32_t rem = sh_rem;
        if (shift == 36) {
            for (int e = tid; e < NPRED; e += 1024) {
                uint64_t k = k_lds[e];
                if ((k >> 14) != INV_HI)
                    atomicAdd(&hist[(uint32_t)(k >> 36) & 4095u], 1u);
            }
            if (tid == 0) atomicAdd(&hist[(uint32_t)(INV_HI >> 22)], sh_inv);
        } else {
            for (int e = tid; e < NPRED; e += 1024) {
                uint64_t k = k_lds[e];
                if ((k & himask) == (pref & himask))
                    atomicAdd(&hist[(uint32_t)(k >> shift) & 4095u], 1u);
            }
        }
        __syncthreads();
        uint32_t h0 = hist[tid * 4 + 0], h1 = hist[tid * 4 + 1];
        uint32_t h2 = hist[tid * 4 + 2], h3 = hist[tid * 4 + 3];
        uint32_t s4 = h0 + h1 + h2 + h3;
        uint32_t v = s4;
        #pragma unroll
        for (int off = 1; off < 64; off <<= 1) {
            uint32_t u = __shfl_down(v, off);
            if (lane + off < 64) v += u;
        }
        if (lane == 0) wtot[wid] = v;
        __syncthreads();
        uint32_t carry = 0;
        for (int w = wid + 1; w < 16; ++w) carry += wtot[w];
        uint32_t S0 = v + carry;
        uint32_t carry_after = S0 - s4;
        if (carry_after < rem && S0 >= rem) {
            uint32_t hh[4] = {h0, h1, h2, h3};
            uint32_t pre = 0, bestS = S0, besth = h0;
            int besti = 0;
            #pragma unroll
            for (int i = 0; i < 4; ++i) {
                uint32_t Si = S0 - pre;
                if (Si >= rem) { besti = i; bestS = Si; besth = hh[i]; }
                pre += hh[i];
            }
            sh_prefix = pref | ((uint64_t)(uint32_t)(tid * 4 + besti) << shift);
            sh_rem = rem - (bestS - besth);
        }
        __syncthreads();
    }

    const uint64_t T = sh_prefix;
    for (int e0 = 0; e0 < NPRED; e0 += 1024) {
        int e = e0 + tid;
        uint64_t k = (e < NPRED) ? k_lds[e] : 0;
        bool pr = (e < NPRED) && (k >= T);
        uint64_t bal = __ballot(pr);
        uint32_t base = 0;
        if (lane == 0 && bal) base = atomicAdd(&sh_cnt, (uint32_t)__popcll(bal));
        base = __shfl(base, 0);
        if (pr) {
            uint32_t pos = base + (uint32_t)__popcll(bal & ((1ull << lane) - 1ull));
            if (pos < 1024) sortbuf[pos] = k;
        }
    }
    __syncthreads();

    uint64_t v64 = sortbuf[tid];
    for (unsigned k = 2; k <= 1024; k <<= 1) {
        for (unsigned j = k >> 1; j > 0; j >>= 1) {
            uint64_t o;
            if (j >= 64) {
                __syncthreads();
                sortbuf[tid] = v64;
                __syncthreads();
                o = sortbuf[tid ^ j];
            } else {
                o = shfl_xor_u64(v64, (int)j);
            }
            bool lower = (tid & j) == 0;
            bool desc = (tid & k) == 0;
            v64 = (lower == desc) ? (v64 > o ? v64 : o) : (v64 < o ? v64 : o);
        }
    }

    uint64_t* lmask = pool;
    float* x1o = (float*)(pool + 16416);
    float* y1o = x1o + TOPK_N;
    float* x2o = y1o + TOPK_N;
    float* y2o = x2o + TOPK_N;
    uint64_t* clsbm = pool + 18416;

    float4 r0 = make_float4(0, 0, 0, 0), r1 = make_float4(0, 0, 0, 0);
    bool invalid = false;
    if (tid < TOPK_N) {
        int e = 16383 - (int)((uint32_t)v64 & 16383u);
        const float4* rp = (const float4*)(recs + ((size_t)b * NPRED + e) * REC_F);
        r0 = rp[0]; r1 = rp[1];
        invalid = (r1.x < CONF_T);
    }
    {
        uint64_t bal = __ballot(invalid);
        if ((tid & 63) == 0) removed_w[tid >> 6] = bal;
    }
    for (int i = tid; i < 16 * NUM_CLASSES; i += 1024) clsbm[i] = 0;
    __syncthreads();

    float ax1 = 0, ay1 = 0, ax2 = 0, ay2 = 0, areai = 0;
    int mycls = 0;
    if (tid < TOPK_N) {
        float offv = __fmul_rn(r1.y, 10.0f);
        ax1 = __fadd_rn(r0.x, offv); ay1 = __fadd_rn(r0.y, offv);
        ax2 = __fadd_rn(r0.z, offv); ay2 = __fadd_rn(r0.w, offv);
        areai = __fmul_rn(__fsub_rn(ax2, ax1), __fsub_rn(ay2, ay1));
        mycls = (int)r1.y;
        x1o[tid] = ax1; y1o[tid] = ay1; x2o[tid] = ax2; y2o[tid] = ay2;
        atomicOr(&clsbm[(tid >> 6) * NUM_CLASSES + mycls], 1ull << (tid & 63));
    }
    __syncthreads();

    const int myw = tid >> 6;
    if (tid < TOPK_N) {
        for (int w = 0; w < 16; ++w) {
            uint64_t bits = 0;
            if (w >= myw) {
                uint64_t bm = clsbm[w * NUM_CLASSES + mycls];
                if (w == myw) bm &= ~((2ull << (tid & 63)) - 1ull);
                while (bm) {
                    int bb = __builtin_ctzll(bm);
                    bm &= bm - 1;
                    int j = w * 64 + bb;
                    float jx1 = x1o[j], jy1 = y1o[j], jx2 = x2o[j], jy2 = y2o[j];
                    float areaj = __fmul_rn(__fsub_rn(jx2, jx1), __fsub_rn(jy2, jy1));
                    float ix1 = fmaxf(ax1, jx1), iy1 = fmaxf(ay1, jy1);
                    float ix2 = fminf(ax2, jx2), iy2 = fminf(ay2, jy2);
                    float dx = fmaxf(__fsub_rn(ix2, ix1), 0.0f);
                    float dy = fmaxf(__fsub_rn(iy2, iy1), 0.0f);
                    float inter = __fmul_rn(dx, dy);
                    float uni = __fsub_rn(__fadd_rn(areai, areaj), inter);
                    float iou = __fdiv_rn(inter, fmaxf(uni, 1e-9f));
                    if (iou > NMS_T) bits |= (1ull << bb);
                }
            }
            lmask[w * MPAD + tid] = bits;
        }
    } else {
        #pragma unroll
        for (int w = 0; w < 16; ++w) lmask[w * MPAD + tid] = 0;
    }
    __syncthreads();

    if (tid < 64) {
        const int l = tid & 15;
        uint64_t rem = (tid < 16) ? removed_w[tid] : 0;
        for (int W = 0; W < 16; ++W) {
            uint64_t cur = __shfl(rem, W);
            const int base = W * 64;
            #pragma unroll
            for (int sb = 0; sb < 64; sb += 16) {
                uint64_t mW[16], ml[16];
                #pragma unroll
                for (int q = 0; q < 16; ++q) {
                    int i = base + sb + q;
                    mW[q] = lmask[W * MPAD + i];
                    ml[q] = lmask[l * MPAD + i];
                }
                #pragma unroll
                for (int q = 0; q < 16; ++q) {
                    int bb = sb + q;
                    uint64_t sel = ((cur >> bb) & 1ull) ? 0ull : ~0ull;
                    cur |= (mW[q] & sel);
                    rem |= (ml[q] & sel);
                }
            }
        }
        if (tid < 16) removed_w[tid] = rem;
    }
    __syncthreads();

    if (tid < TOPK_N) {
        bool kept = ((removed_w[tid >> 6] >> (tid & 63)) & 1ull) == 0;
        float* dr = dets + ((size_t)b * TOPK_N + tid) * 6;
        if (kept) {
            dr[0] = r0.x; dr[1] = r0.y; dr[2] = r0.z; dr[3] = r0.w;
            dr[4] = r1.x; dr[5] = r1.y;
        } else {
            dr[0] = 0.0f; dr[1] = 0.0f; dr[2] = 0.0f;
            dr[3] = 0.0f; dr[4] = 0.0f; dr[5] = 0.0f;
        }
        keep_out[b * TOPK_N + tid] = kept ? 1.0f : 0.0f;
    }
}

// ultra-fallback (tiny ws): one-block-per-batch bitonic topk + LDS nms
__global__ __launch_bounds__(1024) void topk_kernel(const float* __restrict__ pred,
                                                    int* __restrict__ top_idx) {
    __shared__ uint64_t keys[SORTN];
    const int b = blockIdx.x;
    const int tid = threadIdx.x;
    const float* pb = pred + (size_t)b * NPRED * STRIDE;

    for (int e = tid; e < SORTN; e += 1024) {
        uint64_t key = 0;
        if (e < NPRED) {
            const float* p = pb + (size_t)e * STRIDE;
            float obj = p[4];
            float best = p[5];
            #pragma unroll 8
            for (int c = 1; c < NUM_CLASSES; ++c) best = fmaxf(best, p[5 + c]);
            float score = __fmul_rn(obj, best);
            float masked = (score >= CONF_T) ? score : -1.0f;
            key = ((uint64_t)f32_sortable(masked) << 32) | (uint32_t)(~(uint32_t)e);
        }
        keys[e] = key;
    }
    __syncthreads();
    for (unsigned k = 2; k <= SORTN; k <<= 1) {
        for (unsigned j = k >> 1; j > 0; j >>= 1) {
            for (unsigned i = tid; i < SORTN; i += 1024) {
                unsigned ixj = i ^ j;
                if (ixj > i) {
                    uint64_t a = keys[i], c = keys[ixj];
                    bool desc = ((i & k) == 0);
                    if (desc ? (a < c) : (a > c)) { keys[i] = c; keys[ixj] = a; }
                }
            }
            __syncthreads();
        }
    }
    for (int t = tid; t < TOPK_N; t += 1024) {
        top_idx[b * TOPK_N + t] = (int)(~(uint32_t)keys[t]);
    }
}

__global__ __launch_bounds__(1024) void nms_kernel(const float* __restrict__ pred,
                                                   const int* __restrict__ top_idx,
                                                   float* __restrict__ dets,
                                                   float* __restrict__ keep_out) {
    __shared__ uint64_t mask[TOPK_N * 16];
    __shared__ float lx1[TOPK_N], ly1[TOPK_N], lx2[TOPK_N], ly2[TOPK_N];
    __shared__ float lsc[TOPK_N], lcl[TOPK_N];
    __shared__ uint64_t removed_w[16];

    const int b = blockIdx.x;
    const int tid = threadIdx.x;
    const float* pb = pred + (size_t)b * NPRED * STRIDE;

    bool invalid = false;
    if (tid < TOPK_N) {
        int e = top_idx[b * TOPK_N + tid];
        const float* p = pb + (size_t)e * STRIDE;
        float cx = p[0], cy = p[1], w = p[2], h = p[3], obj = p[4];
        float best = p[5]; int bc = 0;
        for (int c = 1; c < NUM_CLASSES; ++c) {
            float v = p[5 + c];
            if (v > best) { best = v; bc = c; }
        }
        float w2 = __fmul_rn(w, 0.5f), h2 = __fmul_rn(h, 0.5f);
        float score = __fmul_rn(obj, best);
        lx1[tid] = __fsub_rn(cx, w2);
        ly1[tid] = __fsub_rn(cy, h2);
        lx2[tid] = __fadd_rn(cx, w2);
        ly2[tid] = __fadd_rn(cy, h2);
        lsc[tid] = score;
        lcl[tid] = (float)bc;
        invalid = (score < CONF_T);
    }
    {
        uint64_t bal = __ballot(invalid);
        if ((tid & 63) == 0) removed_w[tid >> 6] = bal;
    }
    __syncthreads();

    for (int p = tid; p < TOPK_N * 16; p += 1024) {
        int i = p >> 4, w = p & 15;
        float ci = lcl[i];
        float offi = __fmul_rn(ci, 10.0f);
        float ax1 = __fadd_rn(lx1[i], offi), ay1 = __fadd_rn(ly1[i], offi);
        float ax2 = __fadd_rn(lx2[i], offi), ay2 = __fadd_rn(ly2[i], offi);
        float areai = __fmul_rn(__fsub_rn(ax2, ax1), __fsub_rn(ay2, ay1));
        uint64_t bits = 0;
        int jend = min(TOPK_N - w * 64, 64);
        for (int bb = 0; bb < jend; ++bb) {
            int j = w * 64 + bb;
            if (j <= i) continue;
            if (lcl[j] != ci) continue;
            float bx1 = __fadd_rn(lx1[j], offi), by1 = __fadd_rn(ly1[j], offi);
            float bx2 = __fadd_rn(lx2[j], offi), by2 = __fadd_rn(ly2[j], offi);
            float areaj = __fmul_rn(__fsub_rn(bx2, bx1), __fsub_rn(by2, by1));
            float ix1 = fmaxf(ax1, bx1), iy1 = fmaxf(ay1, by1);
            float ix2 = fminf(ax2, bx2), iy2 = fminf(ay2, by2);
            float dx = fmaxf(__fsub_rn(ix2, ix1), 0.0f);
            float dy = fmaxf(__fsub_rn(iy2, iy1), 0.0f);
            float inter = __fmul_rn(dx, dy);
            float uni = __fsub_rn(__fadd_rn(areai, areaj), inter);
            float iou = __fdiv_rn(inter, fmaxf(uni, 1e-9f));
            if (iou > NMS_T) bits |= (1ull << bb);
        }
        mask[i * 16 + w] = bits;
    }
    __syncthreads();

    if (tid < 64) {
        int lane = tid;
        uint64_t rem = (lane < 16) ? removed_w[lane] : 0;
        for (int i = 0; i < TOPK_N; ++i) {
            uint64_t rw = __shfl(rem, i >> 6);
            bool alive = ((rw >> (i & 63)) & 1ull) == 0;
            uint64_t m = mask[i * 16 + (lane & 15)];
            if (alive && lane < 16) rem |= m;
        }
        if (lane < 16) removed_w[lane] = rem;
    }
    __syncthreads();

    for (int t = tid; t < TOPK_N; t += 1024) {
        bool kept = ((removed_w[t >> 6] >> (t & 63)) & 1ull) == 0;
        float* dr = dets + ((size_t)b * TOPK_N + t) * 6;
        if (kept) {
            dr[0] = lx1[t]; dr[1] = ly1[t]; dr[2] = lx2[t]; dr[3] = ly2[t];
            dr[4] = lsc[t]; dr[5] = lcl[t];
        } else {
            dr[0] = 0.0f; dr[1] = 0.0f; dr[2] = 0.0f;
            dr[3] = 0.0f; dr[4] = 0.0f; dr[5] = 0.0f;
        }
        keep_out[b * TOPK_N + t] = kept ? 1.0f : 0.0f;
    }
}

extern "C" void kernel_launch(void* const* d_in, const int* in_sizes, int n_in,
                              void* d_out, int out_size, void* d_ws, size_t ws_size,
                              hipStream_t stream) {
    const float* pred = (const float*)d_in[0];
    float* dets = (float*)d_out;                              // 32*1000*6
    float* keep = (float*)d_out + (size_t)NBATCH * TOPK_N * 6;

    const size_t total_rows = (size_t)NBATCH * NPRED;         // 268800
    const size_t keys_bytes = total_rows * sizeof(uint64_t);  // 2,150,400
    const size_t recs_bytes = total_rows * REC_F * sizeof(float); // 8,601,600
    const size_t hist_bytes = (size_t)NBATCH * 1024 * sizeof(uint32_t); // 131,072
    const size_t idx_bytes  = (size_t)NBATCH * TOPK_N * sizeof(int);

    uint64_t* keys = (uint64_t*)d_ws;
    float* recs    = (float*)((char*)d_ws + keys_bytes);
    uint32_t* hist_g = (uint32_t*)((char*)d_ws + keys_bytes + recs_bytes);

    if (ws_size >= keys_bytes + recs_bytes + hist_bytes) {
        hipMemsetAsync(hist_g, 0, hist_bytes, stream);
        void* args[] = { (void*)&pred, (void*)&keys, (void*)&recs,
                         (void*)&hist_g, (void*)&dets, (void*)&keep };
        hipError_t err = hipLaunchCooperativeKernel((void*)mega_kernel, dim3(256),
                                                    dim3(1024), args, 0, stream);
        if (err == hipSuccess) return;
        // fall through to non-cooperative path (memset is harmless)
    }
    if (ws_size >= keys_bytes + recs_bytes) {
        decode_kernel<<<(int)(total_rows / ROWS_PB), 256, 0, stream>>>(pred, keys, recs);
        fused_kernel<<<NBATCH, 1024, 0, stream>>>(keys, recs, dets, keep);
    } else {
        int* top_idx = (int*)d_ws;
        topk_kernel<<<NBATCH, 1024, 0, stream>>>(pred, top_idx);
        nms_kernel<<<NBATCH, 1024, 0, stream>>>(pred, top_idx, dets, keep);
    }
}

// Round 11
// 87.196 us; speedup vs baseline: 2.0480x; 2.0480x over previous
//
#include <hip/hip_runtime.h>
#include <cstdint>

#define NUM_CLASSES 80
#define NPRED 8400
#define NBATCH 32
#define TOPK_N 1000
#define SORTN 16384
#define CONF_T 0.25f
#define NMS_T 0.45f
#define STRIDE 85

#define ROWS_PB 128
#define FLOATS_PB (ROWS_PB * STRIDE)   // 10880
#define F4_PB (FLOATS_PB / 4)          // 2720
#define REC_F 8                        // floats per record (padded to 32B)
#define MPAD 1026                      // lmask row stride in words (bank skew)
#define KREG 9                         // ceil(8400/1024) keys per thread in registers

// fused LDS pool layout (64-bit words):
//   select phase: hist (u32 x4096) [0,2048) | sortbuf [2048,3072)
//   mask phase:   lmask 16xMPAD [0,16416) | x1o..y2o [16416,18416) | clsbm [18416,19696)
#define POOLW 19696                    // 157,568 bytes

__device__ __forceinline__ uint32_t f32_sortable(float f) {
    uint32_t u = __float_as_uint(f);
    return u ^ ((u >> 31) ? 0xFFFFFFFFu : 0x80000000u);
}

__device__ __forceinline__ uint64_t shfl_xor_u64(uint64_t x, int m) {
    uint32_t lo = (uint32_t)x, hi = (uint32_t)(x >> 32);
    lo = (uint32_t)__shfl_xor((int)lo, m);
    hi = (uint32_t)__shfl_xor((int)hi, m);
    return ((uint64_t)hi << 32) | lo;
}

// 46-bit key: (sortable(masked_score) << 14) | (16383 - e).
// Descending key order == descending score, ascending index on ties (lax.top_k).
__device__ __forceinline__ uint64_t decode_row(const float* p, int e,
                                               float4* rec0, float4* rec1) {
    float cx = p[0], cy = p[1], w = p[2], h = p[3], obj = p[4];
    float best = p[5]; int bc = 0;
    #pragma unroll
    for (int c = 1; c < NUM_CLASSES; ++c) {
        float v = p[5 + c];
        if (v > best) { best = v; bc = c; }        // first-max wins, like jnp.argmax
    }
    float w2 = __fmul_rn(w, 0.5f), h2 = __fmul_rn(h, 0.5f);
    float score = __fmul_rn(obj, best);
    float masked = (score >= CONF_T) ? score : -1.0f;
    *rec0 = make_float4(__fsub_rn(cx, w2), __fsub_rn(cy, h2),
                        __fadd_rn(cx, w2), __fadd_rn(cy, h2));
    *rec1 = make_float4(score, (float)bc, 0.0f, 0.0f);
    return ((uint64_t)f32_sortable(masked) << 14) | (uint32_t)(16383 - e);
}

// Full-grid decode (2100 x 256): coalesced staging, decode, write keys + recs,
// and accumulate the pass-1 histogram (key>>36, 1024 bins/batch) via a per-block
// LDS hist (2 sub-hists for the batch-straddling tile) flushed with atomics.
__global__ __launch_bounds__(256) void decode_kernel(const float* __restrict__ pred,
                                                     uint64_t* __restrict__ keys,
                                                     float* __restrict__ recs,
                                                     uint32_t* __restrict__ hist_g) {
    __shared__ float s[FLOATS_PB];                 // 42.5 KiB
    __shared__ uint32_t h2[2048];                  // 8 KiB
    const int blk = blockIdx.x;
    const int tid = threadIdx.x;
    const float4* g4 = (const float4*)pred + (size_t)blk * F4_PB;
    float4* s4 = (float4*)s;
    for (int i = tid; i < F4_PB; i += 256) s4[i] = g4[i];
    for (int i = tid; i < 2048; i += 256) h2[i] = 0;
    __syncthreads();

    const int r0r = blk * ROWS_PB;
    const int batchA = r0r / NPRED;
    const int batchB = (r0r + ROWS_PB - 1) / NPRED;
    if (tid < ROWS_PB) {
        int r = r0r + tid;
        int batch = r / NPRED;
        int e = r - batch * NPRED;
        float4 rc0, rc1;
        uint64_t key = decode_row(s + tid * STRIDE, e, &rc0, &rc1);
        keys[r] = key;
        float4* rp = (float4*)(recs + (size_t)r * REC_F);
        rp[0] = rc0; rp[1] = rc1;
        int sel = (batch == batchA) ? 0 : 1;
        atomicAdd(&h2[(sel << 10) + (uint32_t)(key >> 36)], 1u);
    }
    __syncthreads();
    if (hist_g) {
        for (int i = tid; i < 2048; i += 256) {
            uint32_t h = h2[i];
            if (h) {
                int bt = (i < 1024) ? batchA : batchB;
                atomicAdd(&hist_g[(bt << 10) + (i & 1023)], h);
            }
        }
    }
}

// One block per batch. Keys live in 9 registers/thread (no k_lds). Pass 1 from
// precomputed hist_g; passes 2-4 + winner compaction sweep the registers.
// Then bitonic sort, gather, class-bitmap sparse mask build in LDS, greedy scan.
__global__ __launch_bounds__(1024) void fused2_kernel(const uint64_t* __restrict__ keys,
                                                      const float* __restrict__ recs,
                                                      const uint32_t* __restrict__ hist_g,
                                                      float* __restrict__ dets,
                                                      float* __restrict__ keep_out) {
    __shared__ uint64_t pool[POOLW];
    __shared__ uint64_t removed_w[16];
    __shared__ uint32_t wtot[16];
    __shared__ uint32_t sh_rem, sh_cnt;
    __shared__ uint64_t sh_prefix;

    const int b = blockIdx.x;
    const int tid = threadIdx.x;
    const int lane = tid & 63, wid = tid >> 6;

    uint32_t* hist = (uint32_t*)pool;              // 4096 u32
    uint64_t* sortbuf = pool + 2048;               // 1024 words

    // keys -> registers (coalesced, static indexing)
    uint64_t kreg[KREG];
    #pragma unroll
    for (int i = 0; i < KREG; ++i) {
        int e = i * 1024 + tid;
        kreg[i] = (e < NPRED) ? keys[(size_t)b * NPRED + e] : 0;  // pad bin 0: never selected
    }
    uint32_t hmine = hist_g[(b << 10) + tid];      // my pass-1 bin count
    if (tid == 0) { sh_rem = TOPK_N; sh_prefix = 0; sh_cnt = 0; }
    sortbuf[tid] = 0;                              // pads sink (real keys are much larger)
    __syncthreads();

    // pass 1: suffix scan over 1024 bins (1 bin/thread) from precomputed hist
    {
        uint32_t v = hmine;
        #pragma unroll
        for (int off = 1; off < 64; off <<= 1) {   // wave inclusive suffix scan
            uint32_t u = __shfl_down(v, off);
            if (lane + off < 64) v += u;
        }
        if (lane == 0) wtot[wid] = v;
        __syncthreads();
        uint32_t carry = 0;
        for (int w = wid + 1; w < 16; ++w) carry += wtot[w];
        uint32_t S0 = v + carry;                   // count of keys in bins >= tid
        if (S0 >= TOPK_N && S0 - hmine < TOPK_N) { // unique crossing thread (hmine > 0)
            sh_prefix = (uint64_t)(uint32_t)tid << 36;
            sh_rem = TOPK_N - (S0 - hmine);
        }
        __syncthreads();
    }

    // passes 2-4 over registers; himask filter keeps only the chosen-prefix keys (~400)
    for (int shift = 24; shift >= 0; shift -= 12) {
        #pragma unroll
        for (int i = 0; i < 4; ++i) hist[tid * 4 + i] = 0;
        __syncthreads();
        const uint64_t himask = ~0ull << (shift + 12);
        const uint64_t pref = sh_prefix;
        const uint32_t rem = sh_rem;
        #pragma unroll
        for (int i = 0; i < KREG; ++i) {
            uint64_t k = kreg[i];
            if ((k & himask) == (pref & himask))   // pad k=0 can't match (pref bin >= 250)
                atomicAdd(&hist[(uint32_t)(k >> shift) & 4095u], 1u);
        }
        __syncthreads();
        uint32_t h0 = hist[tid * 4 + 0], h1 = hist[tid * 4 + 1];
        uint32_t h2 = hist[tid * 4 + 2], h3 = hist[tid * 4 + 3];
        uint32_t s4 = h0 + h1 + h2 + h3;
        uint32_t v = s4;
        #pragma unroll
        for (int off = 1; off < 64; off <<= 1) {
            uint32_t u = __shfl_down(v, off);
            if (lane + off < 64) v += u;
        }
        if (lane == 0) wtot[wid] = v;
        __syncthreads();
        uint32_t carry = 0;
        for (int w = wid + 1; w < 16; ++w) carry += wtot[w];
        uint32_t S0 = v + carry;                   // suffix sum over bins >= 4*tid
        uint32_t carry_after = S0 - s4;
        if (carry_after < rem && S0 >= rem) {      // exactly one thread crosses
            uint32_t hh[4] = {h0, h1, h2, h3};
            uint32_t pre = 0, bestS = S0, besth = h0;
            int besti = 0;
            #pragma unroll
            for (int i = 0; i < 4; ++i) {          // largest i with S(4t+i) >= rem
                uint32_t Si = S0 - pre;
                if (Si >= rem) { besti = i; bestS = Si; besth = hh[i]; }
                pre += hh[i];
            }
            sh_prefix = pref | ((uint64_t)(uint32_t)(tid * 4 + besti) << shift);
            sh_rem = rem - (bestS - besth);
        }
        __syncthreads();
    }

    // winner compaction from registers (exactly 1000 keys >= T; keys unique)
    const uint64_t T = sh_prefix;
    #pragma unroll
    for (int i = 0; i < KREG; ++i) {
        uint64_t k = kreg[i];
        bool pr = (k >= T);                        // pads (0) always fail
        uint64_t bal = __ballot(pr);
        uint32_t base = 0;
        if (lane == 0 && bal) base = atomicAdd(&sh_cnt, (uint32_t)__popcll(bal));
        base = __shfl(base, 0);
        if (pr) {
            uint32_t pos = base + (uint32_t)__popcll(bal & ((1ull << lane) - 1ull));
            if (pos < 1024) sortbuf[pos] = k;
        }
    }
    __syncthreads();

    // bitonic sort descending: LDS for j>=64, register shfl_xor inside wave
    uint64_t v64 = sortbuf[tid];
    for (unsigned k = 2; k <= 1024; k <<= 1) {
        for (unsigned j = k >> 1; j > 0; j >>= 1) {
            uint64_t o;
            if (j >= 64) {
                __syncthreads();
                sortbuf[tid] = v64;
                __syncthreads();
                o = sortbuf[tid ^ j];
            } else {
                o = shfl_xor_u64(v64, (int)j);
            }
            bool lower = (tid & j) == 0;
            bool desc = (tid & k) == 0;
            v64 = (lower == desc) ? (v64 > o ? v64 : o) : (v64 < o ? v64 : o);
        }
    }

    // ---- gather + class bitmaps + in-LDS mask ----
    uint64_t* lmask = pool;                        // [0, 16416)
    float* x1o = (float*)(pool + 16416);
    float* y1o = x1o + TOPK_N;
    float* x2o = y1o + TOPK_N;
    float* y2o = x2o + TOPK_N;
    uint64_t* clsbm = pool + 18416;                // 16 x 80

    float4 r0 = make_float4(0, 0, 0, 0), r1 = make_float4(0, 0, 0, 0);
    bool invalid = false;
    if (tid < TOPK_N) {
        int e = 16383 - (int)((uint32_t)v64 & 16383u);
        const float4* rp = (const float4*)(recs + ((size_t)b * NPRED + e) * REC_F);
        r0 = rp[0]; r1 = rp[1];
        invalid = (r1.x < CONF_T);
    }
    {
        uint64_t bal = __ballot(invalid);
        if ((tid & 63) == 0) removed_w[tid >> 6] = bal;
    }
    for (int i = tid; i < 16 * NUM_CLASSES; i += 1024) clsbm[i] = 0;
    __syncthreads();                               // select-era LDS reads retired

    float ax1 = 0, ay1 = 0, ax2 = 0, ay2 = 0, areai = 0;
    int mycls = 0;
    if (tid < TOPK_N) {
        float offv = __fmul_rn(r1.y, 10.0f);       // exact: class*10 <= 790
        ax1 = __fadd_rn(r0.x, offv); ay1 = __fadd_rn(r0.y, offv);
        ax2 = __fadd_rn(r0.z, offv); ay2 = __fadd_rn(r0.w, offv);
        areai = __fmul_rn(__fsub_rn(ax2, ax1), __fsub_rn(ay2, ay1));
        mycls = (int)r1.y;
        x1o[tid] = ax1; y1o[tid] = ay1; x2o[tid] = ax2; y2o[tid] = ay2;
        atomicOr(&clsbm[(tid >> 6) * NUM_CLASSES + mycls], 1ull << (tid & 63));
    }
    __syncthreads();

    const int myw = tid >> 6;
    if (tid < TOPK_N) {
        for (int w = 0; w < 16; ++w) {
            uint64_t bits = 0;
            if (w >= myw) {
                uint64_t bm = clsbm[w * NUM_CLASSES + mycls];
                if (w == myw) bm &= ~((2ull << (tid & 63)) - 1ull);  // j > tid only
                while (bm) {                       // ~0.4 set bits expected per chunk
                    int bb = __builtin_ctzll(bm);
                    bm &= bm - 1;
                    int j = w * 64 + bb;
                    float jx1 = x1o[j], jy1 = y1o[j], jx2 = x2o[j], jy2 = y2o[j];
                    float areaj = __fmul_rn(__fsub_rn(jx2, jx1), __fsub_rn(jy2, jy1));
                    float ix1 = fmaxf(ax1, jx1), iy1 = fmaxf(ay1, jy1);
                    float ix2 = fminf(ax2, jx2), iy2 = fminf(ay2, jy2);
                    float dx = fmaxf(__fsub_rn(ix2, ix1), 0.0f);
                    float dy = fmaxf(__fsub_rn(iy2, iy1), 0.0f);
                    float inter = __fmul_rn(dx, dy);
                    float uni = __fsub_rn(__fadd_rn(areai, areaj), inter);
                    float iou = __fdiv_rn(inter, fmaxf(uni, 1e-9f));
                    if (iou > NMS_T) bits |= (1ull << bb);
                }
            }
            lmask[w * MPAD + tid] = bits;          // lane-consecutive -> conflict-free
        }
    } else {
        #pragma unroll
        for (int w = 0; w < 16; ++w) lmask[w * MPAD + tid] = 0;  // phantom rows
    }
    __syncthreads();

    // ---- greedy scan (register preload, VALU chain) ----
    if (tid < 64) {
        const int l = tid & 15;
        uint64_t rem = (tid < 16) ? removed_w[tid] : 0;
        for (int W = 0; W < 16; ++W) {
            uint64_t cur = __shfl(rem, W);         // word W incl. earlier suppressions
            const int base = W * 64;
            #pragma unroll
            for (int sb = 0; sb < 64; sb += 16) {
                uint64_t mW[16], ml[16];
                #pragma unroll
                for (int q = 0; q < 16; ++q) {
                    int i = base + sb + q;
                    mW[q] = lmask[W * MPAD + i];   // broadcast read
                    ml[q] = lmask[l * MPAD + i];   // own-row read
                }
                #pragma unroll
                for (int q = 0; q < 16; ++q) {
                    int bb = sb + q;
                    uint64_t sel = ((cur >> bb) & 1ull) ? 0ull : ~0ull;
                    cur |= (mW[q] & sel);          // mask[i] has no bits <= i
                    rem |= (ml[q] & sel);
                }
            }
        }
        if (tid < 16) removed_w[tid] = rem;
    }
    __syncthreads();

    if (tid < TOPK_N) {
        bool kept = ((removed_w[tid >> 6] >> (tid & 63)) & 1ull) == 0;
        float* dr = dets + ((size_t)b * TOPK_N + tid) * 6;
        if (kept) {
            dr[0] = r0.x; dr[1] = r0.y; dr[2] = r0.z; dr[3] = r0.w;
            dr[4] = r1.x; dr[5] = r1.y;
        } else {
            dr[0] = 0.0f; dr[1] = 0.0f; dr[2] = 0.0f;
            dr[3] = 0.0f; dr[4] = 0.0f; dr[5] = 0.0f;
        }
        keep_out[b * TOPK_N + tid] = kept ? 1.0f : 0.0f;
    }
}

// ---------- fallback kernels (small ws): r1 path ----------

__global__ __launch_bounds__(1024) void topk_kernel(const float* __restrict__ pred,
                                                    int* __restrict__ top_idx) {
    __shared__ uint64_t keys[SORTN];
    const int b = blockIdx.x;
    const int tid = threadIdx.x;
    const float* pb = pred + (size_t)b * NPRED * STRIDE;

    for (int e = tid; e < SORTN; e += 1024) {
        uint64_t key = 0;
        if (e < NPRED) {
            const float* p = pb + (size_t)e * STRIDE;
            float obj = p[4];
            float best = p[5];
            #pragma unroll 8
            for (int c = 1; c < NUM_CLASSES; ++c) best = fmaxf(best, p[5 + c]);
            float score = __fmul_rn(obj, best);
            float masked = (score >= CONF_T) ? score : -1.0f;
            key = ((uint64_t)f32_sortable(masked) << 32) | (uint32_t)(~(uint32_t)e);
        }
        keys[e] = key;
    }
    __syncthreads();
    for (unsigned k = 2; k <= SORTN; k <<= 1) {
        for (unsigned j = k >> 1; j > 0; j >>= 1) {
            for (unsigned i = tid; i < SORTN; i += 1024) {
                unsigned ixj = i ^ j;
                if (ixj > i) {
                    uint64_t a = keys[i], c = keys[ixj];
                    bool desc = ((i & k) == 0);
                    if (desc ? (a < c) : (a > c)) { keys[i] = c; keys[ixj] = a; }
                }
            }
            __syncthreads();
        }
    }
    for (int t = tid; t < TOPK_N; t += 1024) {
        top_idx[b * TOPK_N + t] = (int)(~(uint32_t)keys[t]);
    }
}

__global__ __launch_bounds__(1024) void nms_kernel(const float* __restrict__ pred,
                                                   const int* __restrict__ top_idx,
                                                   float* __restrict__ dets,
                                                   float* __restrict__ keep_out) {
    __shared__ uint64_t mask[TOPK_N * 16];
    __shared__ float lx1[TOPK_N], ly1[TOPK_N], lx2[TOPK_N], ly2[TOPK_N];
    __shared__ float lsc[TOPK_N], lcl[TOPK_N];
    __shared__ uint64_t removed_w[16];

    const int b = blockIdx.x;
    const int tid = threadIdx.x;
    const float* pb = pred + (size_t)b * NPRED * STRIDE;

    bool invalid = false;
    if (tid < TOPK_N) {
        int e = top_idx[b * TOPK_N + tid];
        const float* p = pb + (size_t)e * STRIDE;
        float cx = p[0], cy = p[1], w = p[2], h = p[3], obj = p[4];
        float best = p[5]; int bc = 0;
        for (int c = 1; c < NUM_CLASSES; ++c) {
            float v = p[5 + c];
            if (v > best) { best = v; bc = c; }
        }
        float w2 = __fmul_rn(w, 0.5f), h2 = __fmul_rn(h, 0.5f);
        float score = __fmul_rn(obj, best);
        lx1[tid] = __fsub_rn(cx, w2);
        ly1[tid] = __fsub_rn(cy, h2);
        lx2[tid] = __fadd_rn(cx, w2);
        ly2[tid] = __fadd_rn(cy, h2);
        lsc[tid] = score;
        lcl[tid] = (float)bc;
        invalid = (score < CONF_T);
    }
    {
        uint64_t bal = __ballot(invalid);
        if ((tid & 63) == 0) removed_w[tid >> 6] = bal;
    }
    __syncthreads();

    for (int p = tid; p < TOPK_N * 16; p += 1024) {
        int i = p >> 4, w = p & 15;
        float ci = lcl[i];
        float offi = __fmul_rn(ci, 10.0f);
        float ax1 = __fadd_rn(lx1[i], offi), ay1 = __fadd_rn(ly1[i], offi);
        float ax2 = __fadd_rn(lx2[i], offi), ay2 = __fadd_rn(ly2[i], offi);
        float areai = __fmul_rn(__fsub_rn(ax2, ax1), __fsub_rn(ay2, ay1));
        uint64_t bits = 0;
        int jend = min(TOPK_N - w * 64, 64);
        for (int bb = 0; bb < jend; ++bb) {
            int j = w * 64 + bb;
            if (j <= i) continue;
            if (lcl[j] != ci) continue;
            float bx1 = __fadd_rn(lx1[j], offi), by1 = __fadd_rn(ly1[j], offi);
            float bx2 = __fadd_rn(lx2[j], offi), by2 = __fadd_rn(ly2[j], offi);
            float areaj = __fmul_rn(__fsub_rn(bx2, bx1), __fsub_rn(by2, by1));
            float ix1 = fmaxf(ax1, bx1), iy1 = fmaxf(ay1, by1);
            float ix2 = fminf(ax2, bx2), iy2 = fminf(ay2, by2);
            float dx = fmaxf(__fsub_rn(ix2, ix1), 0.0f);
            float dy = fmaxf(__fsub_rn(iy2, iy1), 0.0f);
            float inter = __fmul_rn(dx, dy);
            float uni = __fsub_rn(__fadd_rn(areai, areaj), inter);
            float iou = __fdiv_rn(inter, fmaxf(uni, 1e-9f));
            if (iou > NMS_T) bits |= (1ull << bb);
        }
        mask[i * 16 + w] = bits;
    }
    __syncthreads();

    if (tid < 64) {
        int lane = tid;
        uint64_t rem = (lane < 16) ? removed_w[lane] : 0;
        for (int i = 0; i < TOPK_N; ++i) {
            uint64_t rw = __shfl(rem, i >> 6);
            bool alive = ((rw >> (i & 63)) & 1ull) == 0;
            uint64_t m = mask[i * 16 + (lane & 15)];
            if (alive && lane < 16) rem |= m;
        }
        if (lane < 16) removed_w[lane] = rem;
    }
    __syncthreads();

    for (int t = tid; t < TOPK_N; t += 1024) {
        bool kept = ((removed_w[t >> 6] >> (t & 63)) & 1ull) == 0;
        float* dr = dets + ((size_t)b * TOPK_N + t) * 6;
        if (kept) {
            dr[0] = lx1[t]; dr[1] = ly1[t]; dr[2] = lx2[t]; dr[3] = ly2[t];
            dr[4] = lsc[t]; dr[5] = lcl[t];
        } else {
            dr[0] = 0.0f; dr[1] = 0.0f; dr[2] = 0.0f;
            dr[3] = 0.0f; dr[4] = 0.0f; dr[5] = 0.0f;
        }
        keep_out[b * TOPK_N + t] = kept ? 1.0f : 0.0f;
    }
}

extern "C" void kernel_launch(void* const* d_in, const int* in_sizes, int n_in,
                              void* d_out, int out_size, void* d_ws, size_t ws_size,
                              hipStream_t stream) {
    const float* pred = (const float*)d_in[0];
    float* dets = (float*)d_out;                              // 32*1000*6
    float* keep = (float*)d_out + (size_t)NBATCH * TOPK_N * 6;

    const size_t total_rows = (size_t)NBATCH * NPRED;         // 268800
    const size_t keys_bytes = total_rows * sizeof(uint64_t);  // 2,150,400
    const size_t recs_bytes = total_rows * REC_F * sizeof(float); // 8,601,600
    const size_t hist_bytes = (size_t)NBATCH * 1024 * sizeof(uint32_t); // 131,072

    if (ws_size >= keys_bytes + recs_bytes + hist_bytes) {
        uint64_t* keys = (uint64_t*)d_ws;
        float* recs    = (float*)((char*)d_ws + keys_bytes);
        uint32_t* hist_g = (uint32_t*)((char*)d_ws + keys_bytes + recs_bytes);

        hipMemsetAsync(hist_g, 0, hist_bytes, stream);
        decode_kernel<<<(int)(total_rows / ROWS_PB), 256, 0, stream>>>(pred, keys, recs, hist_g);
        fused2_kernel<<<NBATCH, 1024, 0, stream>>>(keys, recs, hist_g, dets, keep);
    } else {
        int* top_idx = (int*)d_ws;
        topk_kernel<<<NBATCH, 1024, 0, stream>>>(pred, top_idx);
        nms_kernel<<<NBATCH, 1024, 0, stream>>>(pred, top_idx, dets, keep);
    }
}

// Round 12
// 83.810 us; speedup vs baseline: 2.1307x; 1.0404x over previous
//
#include <hip/hip_runtime.h>
#include <cstdint>

#define NUM_CLASSES 80
#define NPRED 8400
#define NBATCH 32
#define TOPK_N 1000
#define SORTN 16384
#define CONF_T 0.25f
#define NMS_T 0.45f
#define STRIDE 85

#define ROWS_PB 128
#define FLOATS_PB (ROWS_PB * STRIDE)   // 10880
#define F4_PB (FLOATS_PB / 4)          // 2720
#define REC_F 8                        // floats per record (padded to 32B)
#define MPAD 1026                      // lmask row stride in words (bank skew)
#define KREG 9                         // ceil(8400/1024) keys per thread in registers

// nms2 LDS pool layout (64-bit words):
//   lmask 16xMPAD [0,16416) | x1o..y2o (f32 x1000 each) [16416,18416) | clsbm [18416,19696)
#define POOLW 19696                    // 157,568 bytes

__device__ __forceinline__ uint32_t f32_sortable(float f) {
    uint32_t u = __float_as_uint(f);
    return u ^ ((u >> 31) ? 0xFFFFFFFFu : 0x80000000u);
}

__device__ __forceinline__ uint64_t shfl_xor_u64(uint64_t x, int m) {
    uint32_t lo = (uint32_t)x, hi = (uint32_t)(x >> 32);
    lo = (uint32_t)__shfl_xor((int)lo, m);
    hi = (uint32_t)__shfl_xor((int)hi, m);
    return ((uint64_t)hi << 32) | lo;
}

// 46-bit key: (sortable(masked_score) << 14) | (16383 - e).
// Descending key order == descending score, ascending index on ties (lax.top_k).
__device__ __forceinline__ uint64_t decode_row(const float* p, int e,
                                               float4* rec0, float4* rec1) {
    float cx = p[0], cy = p[1], w = p[2], h = p[3], obj = p[4];
    float best = p[5]; int bc = 0;
    #pragma unroll
    for (int c = 1; c < NUM_CLASSES; ++c) {
        float v = p[5 + c];
        if (v > best) { best = v; bc = c; }        // first-max wins, like jnp.argmax
    }
    float w2 = __fmul_rn(w, 0.5f), h2 = __fmul_rn(h, 0.5f);
    float score = __fmul_rn(obj, best);
    float masked = (score >= CONF_T) ? score : -1.0f;
    *rec0 = make_float4(__fsub_rn(cx, w2), __fsub_rn(cy, h2),
                        __fadd_rn(cx, w2), __fadd_rn(cy, h2));
    *rec1 = make_float4(score, (float)bc, 0.0f, 0.0f);
    return ((uint64_t)f32_sortable(masked) << 14) | (uint32_t)(16383 - e);
}

// Full-grid decode (2100 x 256, r9 version): coalesced staging, decode,
// write keys + 32B records. No histogram, no memset dependency.
__global__ __launch_bounds__(256) void decode_kernel(const float* __restrict__ pred,
                                                     uint64_t* __restrict__ keys,
                                                     float* __restrict__ recs) {
    __shared__ float s[FLOATS_PB];                 // 42.5 KiB
    const int blk = blockIdx.x;
    const int tid = threadIdx.x;
    const float4* g4 = (const float4*)pred + (size_t)blk * F4_PB;
    float4* s4 = (float4*)s;
    for (int i = tid; i < F4_PB; i += 256) s4[i] = g4[i];
    __syncthreads();
    if (tid < ROWS_PB) {
        int r = blk * ROWS_PB + tid;
        int e = r % NPRED;
        float4 rc0, rc1;
        uint64_t key = decode_row(s + tid * STRIDE, e, &rc0, &rc1);
        keys[r] = key;
        float4* rp = (float4*)(recs + (size_t)r * REC_F);
        rp[0] = rc0; rp[1] = rc1;
    }
}

// One block per batch: keys in 9 registers; pass-1 hist (1024 bins, key>>36)
// built in-kernel with the invalid-ballot bulk-add (no atomic storm); passes
// 2-4 sweep registers with prefix filter; wave-aggregated compaction; hybrid
// bitonic; writes sorted top_idx.
__global__ __launch_bounds__(1024) void select2_kernel(const uint64_t* __restrict__ keys,
                                                       int* __restrict__ top_idx) {
    __shared__ uint32_t hist[4096];                // 16 KiB
    __shared__ uint64_t sortbuf[1024];             // 8 KiB
    __shared__ uint32_t wtot[16];
    __shared__ uint32_t sh_rem, sh_cnt, sh_inv;
    __shared__ uint64_t sh_prefix;

    const int b = blockIdx.x;
    const int tid = threadIdx.x;
    const int lane = tid & 63, wid = tid >> 6;
    const uint32_t INV_HI = f32_sortable(-1.0f);   // 0x407FFFFF; invalid bin = INV_HI>>22 = 257

    if (tid == 0) { sh_rem = TOPK_N; sh_cnt = 0; sh_inv = 0; sh_prefix = 0; }
    sortbuf[tid] = 0;                              // pads sink
    #pragma unroll
    for (int i = 0; i < 4; ++i) hist[tid * 4 + i] = 0;

    // keys -> registers; ballot-count invalids per wave (no per-key atomic)
    uint64_t kreg[KREG];
    uint32_t invw = 0;
    #pragma unroll
    for (int i = 0; i < KREG; ++i) {
        int e = i * 1024 + tid;
        uint64_t k = (e < NPRED) ? keys[(size_t)b * NPRED + e] : 0;  // pad: high bits 0
        kreg[i] = k;
        uint64_t bal = __ballot((uint32_t)(k >> 14) == INV_HI);
        if (lane == 0) invw += (uint32_t)__popcll(bal);
    }
    if (lane == 0 && invw) atomicAdd(&sh_inv, invw);
    __syncthreads();

    // pass-1 hist over valid keys only (1024 bins: key>>36)
    #pragma unroll
    for (int i = 0; i < KREG; ++i) {
        uint64_t k = kreg[i];
        uint32_t hi = (uint32_t)(k >> 14);
        if (hi != 0 && hi != INV_HI)               // skip pads + invalids
            atomicAdd(&hist[(uint32_t)(k >> 36)], 1u);
    }
    __syncthreads();

    // pass 1: suffix scan, 1 bin/thread; invalid count folded into bin 257
    {
        uint32_t hmine = hist[tid] + ((tid == (int)(INV_HI >> 22)) ? sh_inv : 0u);
        uint32_t v = hmine;
        #pragma unroll
        for (int off = 1; off < 64; off <<= 1) {   // wave inclusive suffix scan
            uint32_t u = __shfl_down(v, off);
            if (lane + off < 64) v += u;
        }
        if (lane == 0) wtot[wid] = v;
        __syncthreads();
        uint32_t carry = 0;
        for (int w = wid + 1; w < 16; ++w) carry += wtot[w];
        uint32_t S0 = v + carry;                   // count of keys in bins >= tid
        if (S0 >= TOPK_N && S0 - hmine < TOPK_N) { // unique crossing thread
            sh_prefix = (uint64_t)(uint32_t)tid << 36;
            sh_rem = TOPK_N - (S0 - hmine);
        }
        __syncthreads();
    }

    // passes 2-4 over registers; prefix filter keeps ~bin-sized subset
    for (int shift = 24; shift >= 0; shift -= 12) {
        #pragma unroll
        for (int i = 0; i < 4; ++i) hist[tid * 4 + i] = 0;
        __syncthreads();
        const uint64_t himask = ~0ull << (shift + 12);
        const uint64_t pref = sh_prefix;
        const uint32_t rem = sh_rem;
        #pragma unroll
        for (int i = 0; i < KREG; ++i) {
            uint64_t k = kreg[i];
            if ((k & himask) == (pref & himask))   // pads (0) can't match: pref bin >= 257
                atomicAdd(&hist[(uint32_t)(k >> shift) & 4095u], 1u);
        }
        __syncthreads();
        uint32_t h0 = hist[tid * 4 + 0], h1 = hist[tid * 4 + 1];
        uint32_t h2 = hist[tid * 4 + 2], h3 = hist[tid * 4 + 3];
        uint32_t s4 = h0 + h1 + h2 + h3;
        uint32_t v = s4;
        #pragma unroll
        for (int off = 1; off < 64; off <<= 1) {
            uint32_t u = __shfl_down(v, off);
            if (lane + off < 64) v += u;
        }
        if (lane == 0) wtot[wid] = v;
        __syncthreads();
        uint32_t carry = 0;
        for (int w = wid + 1; w < 16; ++w) carry += wtot[w];
        uint32_t S0 = v + carry;                   // suffix sum over bins >= 4*tid
        uint32_t carry_after = S0 - s4;
        if (carry_after < rem && S0 >= rem) {      // exactly one thread crosses
            uint32_t hh[4] = {h0, h1, h2, h3};
            uint32_t pre = 0, bestS = S0, besth = h0;
            int besti = 0;
            #pragma unroll
            for (int i = 0; i < 4; ++i) {          // largest i with S(4t+i) >= rem
                uint32_t Si = S0 - pre;
                if (Si >= rem) { besti = i; bestS = Si; besth = hh[i]; }
                pre += hh[i];
            }
            sh_prefix = pref | ((uint64_t)(uint32_t)(tid * 4 + besti) << shift);
            sh_rem = rem - (bestS - besth);
        }
        __syncthreads();
    }

    // winner compaction from registers (exactly 1000 keys >= T; keys unique)
    const uint64_t T = sh_prefix;
    #pragma unroll
    for (int i = 0; i < KREG; ++i) {
        uint64_t k = kreg[i];
        bool pr = (k >= T);                        // pads (0) always fail
        uint64_t bal = __ballot(pr);
        uint32_t base = 0;
        if (lane == 0 && bal) base = atomicAdd(&sh_cnt, (uint32_t)__popcll(bal));
        base = __shfl(base, 0);
        if (pr) {
            uint32_t pos = base + (uint32_t)__popcll(bal & ((1ull << lane) - 1ull));
            if (pos < 1024) sortbuf[pos] = k;
        }
    }
    __syncthreads();

    // bitonic sort descending: LDS for j>=64, register shfl_xor inside wave
    uint64_t v64 = sortbuf[tid];
    for (unsigned k = 2; k <= 1024; k <<= 1) {
        for (unsigned j = k >> 1; j > 0; j >>= 1) {
            uint64_t o;
            if (j >= 64) {
                __syncthreads();
                sortbuf[tid] = v64;
                __syncthreads();
                o = sortbuf[tid ^ j];
            } else {
                o = shfl_xor_u64(v64, (int)j);
            }
            bool lower = (tid & j) == 0;
            bool desc = (tid & k) == 0;
            v64 = (lower == desc) ? (v64 > o ? v64 : o) : (v64 < o ? v64 : o);
        }
    }

    if (tid < TOPK_N)
        top_idx[b * TOPK_N + tid] = 16383 - (int)((uint32_t)v64 & 16383u);
}

// One block per batch: gather records via top_idx, class bitmaps, sparse IoU
// mask straight into LDS, register-preload greedy scan, output.
__global__ __launch_bounds__(1024) void nms2_kernel(const float* __restrict__ recs,
                                                    const int* __restrict__ top_idx,
                                                    float* __restrict__ dets,
                                                    float* __restrict__ keep_out) {
    __shared__ uint64_t pool[POOLW];               // 157,568 B
    __shared__ uint64_t removed_w[16];
    const int b = blockIdx.x, tid = threadIdx.x;

    uint64_t* lmask = pool;                        // [0, 16416)
    float* x1o = (float*)(pool + 16416);
    float* y1o = x1o + TOPK_N;
    float* x2o = y1o + TOPK_N;
    float* y2o = x2o + TOPK_N;
    uint64_t* clsbm = pool + 18416;                // 16 x 80

    float4 r0 = make_float4(0, 0, 0, 0), r1 = make_float4(0, 0, 0, 0);
    bool invalid = false;
    if (tid < TOPK_N) {
        int e = top_idx[b * TOPK_N + tid];
        const float4* rp = (const float4*)(recs + ((size_t)b * NPRED + e) * REC_F);
        r0 = rp[0]; r1 = rp[1];
        invalid = (r1.x < CONF_T);
    }
    {
        uint64_t bal = __ballot(invalid);
        if ((tid & 63) == 0) removed_w[tid >> 6] = bal;
    }
    for (int i = tid; i < 16 * NUM_CLASSES; i += 1024) clsbm[i] = 0;
    __syncthreads();

    float ax1 = 0, ay1 = 0, ax2 = 0, ay2 = 0, areai = 0;
    int mycls = 0;
    if (tid < TOPK_N) {
        float offv = __fmul_rn(r1.y, 10.0f);       // exact: class*10 <= 790
        ax1 = __fadd_rn(r0.x, offv); ay1 = __fadd_rn(r0.y, offv);
        ax2 = __fadd_rn(r0.z, offv); ay2 = __fadd_rn(r0.w, offv);
        areai = __fmul_rn(__fsub_rn(ax2, ax1), __fsub_rn(ay2, ay1));
        mycls = (int)r1.y;
        x1o[tid] = ax1; y1o[tid] = ay1; x2o[tid] = ax2; y2o[tid] = ay2;
        atomicOr(&clsbm[(tid >> 6) * NUM_CLASSES + mycls], 1ull << (tid & 63));
    }
    __syncthreads();

    const int myw = tid >> 6;
    if (tid < TOPK_N) {
        for (int w = 0; w < 16; ++w) {
            uint64_t bits = 0;
            if (w >= myw) {
                uint64_t bm = clsbm[w * NUM_CLASSES + mycls];
                if (w == myw) bm &= ~((2ull << (tid & 63)) - 1ull);  // j > tid only
                while (bm) {                       // ~0.4 set bits expected per chunk
                    int bb = __builtin_ctzll(bm);
                    bm &= bm - 1;
                    int j = w * 64 + bb;
                    float jx1 = x1o[j], jy1 = y1o[j], jx2 = x2o[j], jy2 = y2o[j];
                    float areaj = __fmul_rn(__fsub_rn(jx2, jx1), __fsub_rn(jy2, jy1));
                    float ix1 = fmaxf(ax1, jx1), iy1 = fmaxf(ay1, jy1);
                    float ix2 = fminf(ax2, jx2), iy2 = fminf(ay2, jy2);
                    float dx = fmaxf(__fsub_rn(ix2, ix1), 0.0f);
                    float dy = fmaxf(__fsub_rn(iy2, iy1), 0.0f);
                    float inter = __fmul_rn(dx, dy);
                    float uni = __fsub_rn(__fadd_rn(areai, areaj), inter);
                    float iou = __fdiv_rn(inter, fmaxf(uni, 1e-9f));
                    if (iou > NMS_T) bits |= (1ull << bb);
                }
            }
            lmask[w * MPAD + tid] = bits;          // lane-consecutive -> conflict-free
        }
    } else {
        #pragma unroll
        for (int w = 0; w < 16; ++w) lmask[w * MPAD + tid] = 0;  // phantom rows
    }
    __syncthreads();

    // greedy scan (register preload, VALU chain)
    if (tid < 64) {
        const int l = tid & 15;
        uint64_t rem = (tid < 16) ? removed_w[tid] : 0;
        for (int W = 0; W < 16; ++W) {
            uint64_t cur = __shfl(rem, W);         // word W incl. earlier suppressions
            const int base = W * 64;
            #pragma unroll
            for (int sb = 0; sb < 64; sb += 16) {
                uint64_t mW[16], ml[16];
                #pragma unroll
                for (int q = 0; q < 16; ++q) {
                    int i = base + sb + q;
                    mW[q] = lmask[W * MPAD + i];   // broadcast read
                    ml[q] = lmask[l * MPAD + i];   // own-row read
                }
                #pragma unroll
                for (int q = 0; q < 16; ++q) {
                    int bb = sb + q;
                    uint64_t sel = ((cur >> bb) & 1ull) ? 0ull : ~0ull;
                    cur |= (mW[q] & sel);          // mask[i] has no bits <= i
                    rem |= (ml[q] & sel);
                }
            }
        }
        if (tid < 16) removed_w[tid] = rem;
    }
    __syncthreads();

    if (tid < TOPK_N) {
        bool kept = ((removed_w[tid >> 6] >> (tid & 63)) & 1ull) == 0;
        float* dr = dets + ((size_t)b * TOPK_N + tid) * 6;
        if (kept) {
            dr[0] = r0.x; dr[1] = r0.y; dr[2] = r0.z; dr[3] = r0.w;
            dr[4] = r1.x; dr[5] = r1.y;
        } else {
            dr[0] = 0.0f; dr[1] = 0.0f; dr[2] = 0.0f;
            dr[3] = 0.0f; dr[4] = 0.0f; dr[5] = 0.0f;
        }
        keep_out[b * TOPK_N + tid] = kept ? 1.0f : 0.0f;
    }
}

// ---------- fallback kernels (small ws): r1 path ----------

__global__ __launch_bounds__(1024) void topk_kernel(const float* __restrict__ pred,
                                                    int* __restrict__ top_idx) {
    __shared__ uint64_t keys[SORTN];
    const int b = blockIdx.x;
    const int tid = threadIdx.x;
    const float* pb = pred + (size_t)b * NPRED * STRIDE;

    for (int e = tid; e < SORTN; e += 1024) {
        uint64_t key = 0;
        if (e < NPRED) {
            const float* p = pb + (size_t)e * STRIDE;
            float obj = p[4];
            float best = p[5];
            #pragma unroll 8
            for (int c = 1; c < NUM_CLASSES; ++c) best = fmaxf(best, p[5 + c]);
            float score = __fmul_rn(obj, best);
            float masked = (score >= CONF_T) ? score : -1.0f;
            key = ((uint64_t)f32_sortable(masked) << 32) | (uint32_t)(~(uint32_t)e);
        }
        keys[e] = key;
    }
    __syncthreads();
    for (unsigned k = 2; k <= SORTN; k <<= 1) {
        for (unsigned j = k >> 1; j > 0; j >>= 1) {
            for (unsigned i = tid; i < SORTN; i += 1024) {
                unsigned ixj = i ^ j;
                if (ixj > i) {
                    uint64_t a = keys[i], c = keys[ixj];
                    bool desc = ((i & k) == 0);
                    if (desc ? (a < c) : (a > c)) { keys[i] = c; keys[ixj] = a; }
                }
            }
            __syncthreads();
        }
    }
    for (int t = tid; t < TOPK_N; t += 1024) {
        top_idx[b * TOPK_N + t] = (int)(~(uint32_t)keys[t]);
    }
}

__global__ __launch_bounds__(1024) void nms_kernel(const float* __restrict__ pred,
                                                   const int* __restrict__ top_idx,
                                                   float* __restrict__ dets,
                                                   float* __restrict__ keep_out) {
    __shared__ uint64_t mask[TOPK_N * 16];
    __shared__ float lx1[TOPK_N], ly1[TOPK_N], lx2[TOPK_N], ly2[TOPK_N];
    __shared__ float lsc[TOPK_N], lcl[TOPK_N];
    __shared__ uint64_t removed_w[16];

    const int b = blockIdx.x;
    const int tid = threadIdx.x;
    const float* pb = pred + (size_t)b * NPRED * STRIDE;

    bool invalid = false;
    if (tid < TOPK_N) {
        int e = top_idx[b * TOPK_N + tid];
        const float* p = pb + (size_t)e * STRIDE;
        float cx = p[0], cy = p[1], w = p[2], h = p[3], obj = p[4];
        float best = p[5]; int bc = 0;
        for (int c = 1; c < NUM_CLASSES; ++c) {
            float v = p[5 + c];
            if (v > best) { best = v; bc = c; }
        }
        float w2 = __fmul_rn(w, 0.5f), h2 = __fmul_rn(h, 0.5f);
        float score = __fmul_rn(obj, best);
        lx1[tid] = __fsub_rn(cx, w2);
        ly1[tid] = __fsub_rn(cy, h2);
        lx2[tid] = __fadd_rn(cx, w2);
        ly2[tid] = __fadd_rn(cy, h2);
        lsc[tid] = score;
        lcl[tid] = (float)bc;
        invalid = (score < CONF_T);
    }
    {
        uint64_t bal = __ballot(invalid);
        if ((tid & 63) == 0) removed_w[tid >> 6] = bal;
    }
    __syncthreads();

    for (int p = tid; p < TOPK_N * 16; p += 1024) {
        int i = p >> 4, w = p & 15;
        float ci = lcl[i];
        float offi = __fmul_rn(ci, 10.0f);
        float ax1 = __fadd_rn(lx1[i], offi), ay1 = __fadd_rn(ly1[i], offi);
        float ax2 = __fadd_rn(lx2[i], offi), ay2 = __fadd_rn(ly2[i], offi);
        float areai = __fmul_rn(__fsub_rn(ax2, ax1), __fsub_rn(ay2, ay1));
        uint64_t bits = 0;
        int jend = min(TOPK_N - w * 64, 64);
        for (int bb = 0; bb < jend; ++bb) {
            int j = w * 64 + bb;
            if (j <= i) continue;
            if (lcl[j] != ci) continue;
            float bx1 = __fadd_rn(lx1[j], offi), by1 = __fadd_rn(ly1[j], offi);
            float bx2 = __fadd_rn(lx2[j], offi), by2 = __fadd_rn(ly2[j], offi);
            float areaj = __fmul_rn(__fsub_rn(bx2, bx1), __fsub_rn(by2, by1));
            float ix1 = fmaxf(ax1, bx1), iy1 = fmaxf(ay1, by1);
            float ix2 = fminf(ax2, bx2), iy2 = fminf(ay2, by2);
            float dx = fmaxf(__fsub_rn(ix2, ix1), 0.0f);
            float dy = fmaxf(__fsub_rn(iy2, iy1), 0.0f);
            float inter = __fmul_rn(dx, dy);
            float uni = __fsub_rn(__fadd_rn(areai, areaj), inter);
            float iou = __fdiv_rn(inter, fmaxf(uni, 1e-9f));
            if (iou > NMS_T) bits |= (1ull << bb);
        }
        mask[i * 16 + w] = bits;
    }
    __syncthreads();

    if (tid < 64) {
        int lane = tid;
        uint64_t rem = (lane < 16) ? removed_w[lane] : 0;
        for (int i = 0; i < TOPK_N; ++i) {
            uint64_t rw = __shfl(rem, i >> 6);
            bool alive = ((rw >> (i & 63)) & 1ull) == 0;
            uint64_t m = mask[i * 16 + (lane & 15)];
            if (alive && lane < 16) rem |= m;
        }
        if (lane < 16) removed_w[lane] = rem;
    }
    __syncthreads();

    for (int t = tid; t < TOPK_N; t += 1024) {
        bool kept = ((removed_w[t >> 6] >> (t & 63)) & 1ull) == 0;
        float* dr = dets + ((size_t)b * TOPK_N + t) * 6;
        if (kept) {
            dr[0] = lx1[t]; dr[1] = ly1[t]; dr[2] = lx2[t]; dr[3] = ly2[t];
            dr[4] = lsc[t]; dr[5] = lcl[t];
        } else {
            dr[0] = 0.0f; dr[1] = 0.0f; dr[2] = 0.0f;
            dr[3] = 0.0f; dr[4] = 0.0f; dr[5] = 0.0f;
        }
        keep_out[b * TOPK_N + t] = kept ? 1.0f : 0.0f;
    }
}

extern "C" void kernel_launch(void* const* d_in, const int* in_sizes, int n_in,
                              void* d_out, int out_size, void* d_ws, size_t ws_size,
                              hipStream_t stream) {
    const float* pred = (const float*)d_in[0];
    float* dets = (float*)d_out;                              // 32*1000*6
    float* keep = (float*)d_out + (size_t)NBATCH * TOPK_N * 6;

    const size_t total_rows = (size_t)NBATCH * NPRED;         // 268800
    const size_t keys_bytes = total_rows * sizeof(uint64_t);  // 2,150,400
    const size_t recs_bytes = total_rows * REC_F * sizeof(float); // 8,601,600
    const size_t idx_bytes  = (size_t)NBATCH * TOPK_N * sizeof(int); // 128,000

    if (ws_size >= keys_bytes + recs_bytes + idx_bytes) {
        uint64_t* keys = (uint64_t*)d_ws;
        float* recs    = (float*)((char*)d_ws + keys_bytes);
        int* top_idx   = (int*)((char*)d_ws + keys_bytes + recs_bytes);

        decode_kernel<<<(int)(total_rows / ROWS_PB), 256, 0, stream>>>(pred, keys, recs);
        select2_kernel<<<NBATCH, 1024, 0, stream>>>(keys, top_idx);
        nms2_kernel<<<NBATCH, 1024, 0, stream>>>(recs, top_idx, dets, keep);
    } else {
        int* top_idx = (int*)d_ws;
        topk_kernel<<<NBATCH, 1024, 0, stream>>>(pred, top_idx);
        nms_kernel<<<NBATCH, 1024, 0, stream>>>(pred, top_idx, dets, keep);
    }
}

// Round 13
// 82.964 us; speedup vs baseline: 2.1525x; 1.0102x over previous
//
#include <hip/hip_runtime.h>
#include <cstdint>

#define NUM_CLASSES 80
#define NPRED 8400
#define NBATCH 32
#define TOPK_N 1000
#define SORTN 16384
#define CONF_T 0.25f
#define NMS_T 0.45f
#define STRIDE 85

#define ROWS_PB 128
#define FLOATS_PB (ROWS_PB * STRIDE)   // 10880
#define F4_PB (FLOATS_PB / 4)          // 2720
#define REC_F 8                        // floats per record (padded to 32B)
#define MPAD 1026                      // lmask row stride in words (bank skew, even)
#define KREG 9                         // ceil(8400/1024) keys per thread in registers

// nms2 LDS pool layout (64-bit words):
//   lmask 16xMPAD [0,16416) | x1o..y2o (f32 x1000 each) [16416,18416) | clsbm [18416,19696)
#define POOLW 19696                    // 157,568 bytes

__device__ __forceinline__ uint32_t f32_sortable(float f) {
    uint32_t u = __float_as_uint(f);
    return u ^ ((u >> 31) ? 0xFFFFFFFFu : 0x80000000u);
}

__device__ __forceinline__ uint64_t shfl_xor_u64(uint64_t x, int m) {
    uint32_t lo = (uint32_t)x, hi = (uint32_t)(x >> 32);
    lo = (uint32_t)__shfl_xor((int)lo, m);
    hi = (uint32_t)__shfl_xor((int)hi, m);
    return ((uint64_t)hi << 32) | lo;
}

// 46-bit key: (sortable(masked_score) << 14) | (16383 - e).
// Descending key order == descending score, ascending index on ties (lax.top_k).
__device__ __forceinline__ uint64_t decode_row(const float* p, int e,
                                               float4* rec0, float4* rec1) {
    float cx = p[0], cy = p[1], w = p[2], h = p[3], obj = p[4];
    float best = p[5]; int bc = 0;
    #pragma unroll
    for (int c = 1; c < NUM_CLASSES; ++c) {
        float v = p[5 + c];
        if (v > best) { best = v; bc = c; }        // first-max wins, like jnp.argmax
    }
    float w2 = __fmul_rn(w, 0.5f), h2 = __fmul_rn(h, 0.5f);
    float score = __fmul_rn(obj, best);
    float masked = (score >= CONF_T) ? score : -1.0f;
    *rec0 = make_float4(__fsub_rn(cx, w2), __fsub_rn(cy, h2),
                        __fadd_rn(cx, w2), __fadd_rn(cy, h2));
    *rec1 = make_float4(score, (float)bc, 0.0f, 0.0f);
    return ((uint64_t)f32_sortable(masked) << 14) | (uint32_t)(16383 - e);
}

// Full-grid decode (2100 x 256): coalesced staging, decode, write keys + recs.
__global__ __launch_bounds__(256) void decode_kernel(const float* __restrict__ pred,
                                                     uint64_t* __restrict__ keys,
                                                     float* __restrict__ recs) {
    __shared__ float s[FLOATS_PB];                 // 42.5 KiB
    const int blk = blockIdx.x;
    const int tid = threadIdx.x;
    const float4* g4 = (const float4*)pred + (size_t)blk * F4_PB;
    float4* s4 = (float4*)s;
    for (int i = tid; i < F4_PB; i += 256) s4[i] = g4[i];
    __syncthreads();
    if (tid < ROWS_PB) {
        int r = blk * ROWS_PB + tid;
        int e = r % NPRED;
        float4 rc0, rc1;
        uint64_t key = decode_row(s + tid * STRIDE, e, &rc0, &rc1);
        keys[r] = key;
        float4* rp = (float4*)(recs + (size_t)r * REC_F);
        rp[0] = rc0; rp[1] = rc1;
    }
}

// One block per batch: keys in 9 registers; pass-1 hist built in-kernel with
// invalid-ballot bulk-add; passes 2-4 sweep registers; wave-aggregated
// compaction; hybrid bitonic; writes sorted top_idx.
__global__ __launch_bounds__(1024) void select2_kernel(const uint64_t* __restrict__ keys,
                                                       int* __restrict__ top_idx) {
    __shared__ uint32_t hist[4096];                // 16 KiB
    __shared__ uint64_t sortbuf[1024];             // 8 KiB
    __shared__ uint32_t wtot[16];
    __shared__ uint32_t sh_rem, sh_cnt, sh_inv;
    __shared__ uint64_t sh_prefix;

    const int b = blockIdx.x;
    const int tid = threadIdx.x;
    const int lane = tid & 63, wid = tid >> 6;
    const uint32_t INV_HI = f32_sortable(-1.0f);   // 0x407FFFFF; invalid bin = 257

    if (tid == 0) { sh_rem = TOPK_N; sh_cnt = 0; sh_inv = 0; sh_prefix = 0; }
    sortbuf[tid] = 0;                              // pads sink
    #pragma unroll
    for (int i = 0; i < 4; ++i) hist[tid * 4 + i] = 0;

    // keys -> registers; ballot-count invalids per wave (no per-key atomic)
    uint64_t kreg[KREG];
    uint32_t invw = 0;
    #pragma unroll
    for (int i = 0; i < KREG; ++i) {
        int e = i * 1024 + tid;
        uint64_t k = (e < NPRED) ? keys[(size_t)b * NPRED + e] : 0;  // pad: high bits 0
        kreg[i] = k;
        uint64_t bal = __ballot((uint32_t)(k >> 14) == INV_HI);
        if (lane == 0) invw += (uint32_t)__popcll(bal);
    }
    if (lane == 0 && invw) atomicAdd(&sh_inv, invw);
    __syncthreads();

    // pass-1 hist over valid keys only (1024 bins: key>>36)
    #pragma unroll
    for (int i = 0; i < KREG; ++i) {
        uint64_t k = kreg[i];
        uint32_t hi = (uint32_t)(k >> 14);
        if (hi != 0 && hi != INV_HI)               // skip pads + invalids
            atomicAdd(&hist[(uint32_t)(k >> 36)], 1u);
    }
    __syncthreads();

    // pass 1: suffix scan, 1 bin/thread; invalid count folded into bin 257
    {
        uint32_t hmine = hist[tid] + ((tid == (int)(INV_HI >> 22)) ? sh_inv : 0u);
        uint32_t v = hmine;
        #pragma unroll
        for (int off = 1; off < 64; off <<= 1) {   // wave inclusive suffix scan
            uint32_t u = __shfl_down(v, off);
            if (lane + off < 64) v += u;
        }
        if (lane == 0) wtot[wid] = v;
        __syncthreads();
        uint32_t carry = 0;
        for (int w = wid + 1; w < 16; ++w) carry += wtot[w];
        uint32_t S0 = v + carry;                   // count of keys in bins >= tid
        if (S0 >= TOPK_N && S0 - hmine < TOPK_N) { // unique crossing thread
            sh_prefix = (uint64_t)(uint32_t)tid << 36;
            sh_rem = TOPK_N - (S0 - hmine);
        }
        __syncthreads();
    }

    // passes 2-4 over registers; prefix filter keeps ~bin-sized subset
    for (int shift = 24; shift >= 0; shift -= 12) {
        #pragma unroll
        for (int i = 0; i < 4; ++i) hist[tid * 4 + i] = 0;
        __syncthreads();
        const uint64_t himask = ~0ull << (shift + 12);
        const uint64_t pref = sh_prefix;
        const uint32_t rem = sh_rem;
        #pragma unroll
        for (int i = 0; i < KREG; ++i) {
            uint64_t k = kreg[i];
            if ((k & himask) == (pref & himask))   // pads (0) can't match: pref bin >= 257
                atomicAdd(&hist[(uint32_t)(k >> shift) & 4095u], 1u);
        }
        __syncthreads();
        uint32_t h0 = hist[tid * 4 + 0], h1 = hist[tid * 4 + 1];
        uint32_t h2 = hist[tid * 4 + 2], h3 = hist[tid * 4 + 3];
        uint32_t s4 = h0 + h1 + h2 + h3;
        uint32_t v = s4;
        #pragma unroll
        for (int off = 1; off < 64; off <<= 1) {
            uint32_t u = __shfl_down(v, off);
            if (lane + off < 64) v += u;
        }
        if (lane == 0) wtot[wid] = v;
        __syncthreads();
        uint32_t carry = 0;
        for (int w = wid + 1; w < 16; ++w) carry += wtot[w];
        uint32_t S0 = v + carry;                   // suffix sum over bins >= 4*tid
        uint32_t carry_after = S0 - s4;
        if (carry_after < rem && S0 >= rem) {      // exactly one thread crosses
            uint32_t hh[4] = {h0, h1, h2, h3};
            uint32_t pre = 0, bestS = S0, besth = h0;
            int besti = 0;
            #pragma unroll
            for (int i = 0; i < 4; ++i) {          // largest i with S(4t+i) >= rem
                uint32_t Si = S0 - pre;
                if (Si >= rem) { besti = i; bestS = Si; besth = hh[i]; }
                pre += hh[i];
            }
            sh_prefix = pref | ((uint64_t)(uint32_t)(tid * 4 + besti) << shift);
            sh_rem = rem - (bestS - besth);
        }
        __syncthreads();
    }

    // winner compaction from registers (exactly 1000 keys >= T; keys unique)
    const uint64_t T = sh_prefix;
    #pragma unroll
    for (int i = 0; i < KREG; ++i) {
        uint64_t k = kreg[i];
        bool pr = (k >= T);                        // pads (0) always fail
        uint64_t bal = __ballot(pr);
        uint32_t base = 0;
        if (lane == 0 && bal) base = atomicAdd(&sh_cnt, (uint32_t)__popcll(bal));
        base = __shfl(base, 0);
        if (pr) {
            uint32_t pos = base + (uint32_t)__popcll(bal & ((1ull << lane) - 1ull));
            if (pos < 1024) sortbuf[pos] = k;
        }
    }
    __syncthreads();

    // bitonic sort descending: LDS for j>=64, register shfl_xor inside wave
    uint64_t v64 = sortbuf[tid];
    for (unsigned k = 2; k <= 1024; k <<= 1) {
        for (unsigned j = k >> 1; j > 0; j >>= 1) {
            uint64_t o;
            if (j >= 64) {
                __syncthreads();
                sortbuf[tid] = v64;
                __syncthreads();
                o = sortbuf[tid ^ j];
            } else {
                o = shfl_xor_u64(v64, (int)j);
            }
            bool lower = (tid & j) == 0;
            bool desc = (tid & k) == 0;
            v64 = (lower == desc) ? (v64 > o ? v64 : o) : (v64 < o ? v64 : o);
        }
    }

    if (tid < TOPK_N)
        top_idx[b * TOPK_N + tid] = 16383 - (int)((uint32_t)v64 & 16383u);
}

// One block per batch: gather records via top_idx, class bitmaps, sparse IoU
// mask straight into LDS, register-preload greedy scan, output.
// __launch_bounds__(1024, 1): min 1 wave/EU -> VGPR allocator unconstrained
// (LDS already caps us at 1 block/CU); the scan's 2x16-word preload must live
// in VGPRs, not be re-fused into a serial load->use chain at a ~52-VGPR cap.
__global__ __launch_bounds__(1024, 1) void nms2_kernel(const float* __restrict__ recs,
                                                       const int* __restrict__ top_idx,
                                                       float* __restrict__ dets,
                                                       float* __restrict__ keep_out) {
    __shared__ uint64_t pool[POOLW];               // 157,568 B
    __shared__ uint64_t removed_w[16];
    const int b = blockIdx.x, tid = threadIdx.x;

    uint64_t* lmask = pool;                        // [0, 16416)
    float* x1o = (float*)(pool + 16416);
    float* y1o = x1o + TOPK_N;
    float* x2o = y1o + TOPK_N;
    float* y2o = x2o + TOPK_N;
    uint64_t* clsbm = pool + 18416;                // 16 x 80

    float4 r0 = make_float4(0, 0, 0, 0), r1 = make_float4(0, 0, 0, 0);
    bool invalid = false;
    if (tid < TOPK_N) {
        int e = top_idx[b * TOPK_N + tid];
        const float4* rp = (const float4*)(recs + ((size_t)b * NPRED + e) * REC_F);
        r0 = rp[0]; r1 = rp[1];
        invalid = (r1.x < CONF_T);
    }
    {
        uint64_t bal = __ballot(invalid);
        if ((tid & 63) == 0) removed_w[tid >> 6] = bal;
    }
    for (int i = tid; i < 16 * NUM_CLASSES; i += 1024) clsbm[i] = 0;
    __syncthreads();

    float ax1 = 0, ay1 = 0, ax2 = 0, ay2 = 0, areai = 0;
    int mycls = 0;
    if (tid < TOPK_N) {
        float offv = __fmul_rn(r1.y, 10.0f);       // exact: class*10 <= 790
        ax1 = __fadd_rn(r0.x, offv); ay1 = __fadd_rn(r0.y, offv);
        ax2 = __fadd_rn(r0.z, offv); ay2 = __fadd_rn(r0.w, offv);
        areai = __fmul_rn(__fsub_rn(ax2, ax1), __fsub_rn(ay2, ay1));
        mycls = (int)r1.y;
        x1o[tid] = ax1; y1o[tid] = ay1; x2o[tid] = ax2; y2o[tid] = ay2;
        atomicOr(&clsbm[(tid >> 6) * NUM_CLASSES + mycls], 1ull << (tid & 63));
    }
    __syncthreads();

    const int myw = tid >> 6;
    if (tid < TOPK_N) {
        for (int w = 0; w < 16; ++w) {
            uint64_t bits = 0;
            if (w >= myw) {
                uint64_t bm = clsbm[w * NUM_CLASSES + mycls];
                if (w == myw) bm &= ~((2ull << (tid & 63)) - 1ull);  // j > tid only
                while (bm) {                       // ~0.4 set bits expected per chunk
                    int bb = __builtin_ctzll(bm);
                    bm &= bm - 1;
                    int j = w * 64 + bb;
                    float jx1 = x1o[j], jy1 = y1o[j], jx2 = x2o[j], jy2 = y2o[j];
                    float areaj = __fmul_rn(__fsub_rn(jx2, jx1), __fsub_rn(jy2, jy1));
                    float ix1 = fmaxf(ax1, jx1), iy1 = fmaxf(ay1, jy1);
                    float ix2 = fminf(ax2, jx2), iy2 = fminf(ay2, jy2);
                    float dx = fmaxf(__fsub_rn(ix2, ix1), 0.0f);
                    float dy = fmaxf(__fsub_rn(iy2, iy1), 0.0f);
                    float inter = __fmul_rn(dx, dy);
                    float uni = __fsub_rn(__fadd_rn(areai, areaj), inter);
                    float iou = __fdiv_rn(inter, fmaxf(uni, 1e-9f));
                    if (iou > NMS_T) bits |= (1ull << bb);
                }
            }
            lmask[w * MPAD + tid] = bits;          // lane-consecutive -> conflict-free
        }
    } else {
        #pragma unroll
        for (int w = 0; w < 16; ++w) lmask[w * MPAD + tid] = 0;  // phantom rows
    }
    __syncthreads();

    // greedy scan: one wave; per 16-column group, preload 2x16 words as 16B
    // LDS reads into registers (now actually fit), then a pure-VALU chain.
    if (tid < 64) {
        const int l = tid & 15;
        uint64_t rem = (tid < 16) ? removed_w[tid] : 0;
        for (int W = 0; W < 16; ++W) {
            uint64_t cur = __shfl(rem, W);         // word W incl. earlier suppressions
            const int base = W * 64;
            #pragma unroll
            for (int sb = 0; sb < 64; sb += 16) {
                ulonglong2 mW2[8], ml2[8];
                #pragma unroll
                for (int q = 0; q < 8; ++q) {
                    int i = base + sb + 2 * q;     // even word index -> 16B aligned
                    mW2[q] = *(const ulonglong2*)&lmask[W * MPAD + i];  // broadcast
                    ml2[q] = *(const ulonglong2*)&lmask[l * MPAD + i];  // own row
                }
                #pragma unroll
                for (int q = 0; q < 8; ++q) {
                    int bb = sb + 2 * q;
                    uint64_t sel0 = ((cur >> bb) & 1ull) ? 0ull : ~0ull;
                    cur |= (mW2[q].x & sel0);      // mask[i] has no bits <= i
                    rem |= (ml2[q].x & sel0);
                    uint64_t sel1 = ((cur >> (bb + 1)) & 1ull) ? 0ull : ~0ull;
                    cur |= (mW2[q].y & sel1);
                    rem |= (ml2[q].y & sel1);
                }
            }
        }
        if (tid < 16) removed_w[tid] = rem;
    }
    __syncthreads();

    if (tid < TOPK_N) {
        bool kept = ((removed_w[tid >> 6] >> (tid & 63)) & 1ull) == 0;
        float* dr = dets + ((size_t)b * TOPK_N + tid) * 6;
        if (kept) {
            dr[0] = r0.x; dr[1] = r0.y; dr[2] = r0.z; dr[3] = r0.w;
            dr[4] = r1.x; dr[5] = r1.y;
        } else {
            dr[0] = 0.0f; dr[1] = 0.0f; dr[2] = 0.0f;
            dr[3] = 0.0f; dr[4] = 0.0f; dr[5] = 0.0f;
        }
        keep_out[b * TOPK_N + tid] = kept ? 1.0f : 0.0f;
    }
}

// ---------- fallback kernels (small ws): r1 path ----------

__global__ __launch_bounds__(1024) void topk_kernel(const float* __restrict__ pred,
                                                    int* __restrict__ top_idx) {
    __shared__ uint64_t keys[SORTN];
    const int b = blockIdx.x;
    const int tid = threadIdx.x;
    const float* pb = pred + (size_t)b * NPRED * STRIDE;

    for (int e = tid; e < SORTN; e += 1024) {
        uint64_t key = 0;
        if (e < NPRED) {
            const float* p = pb + (size_t)e * STRIDE;
            float obj = p[4];
            float best = p[5];
            #pragma unroll 8
            for (int c = 1; c < NUM_CLASSES; ++c) best = fmaxf(best, p[5 + c]);
            float score = __fmul_rn(obj, best);
            float masked = (score >= CONF_T) ? score : -1.0f;
            key = ((uint64_t)f32_sortable(masked) << 32) | (uint32_t)(~(uint32_t)e);
        }
        keys[e] = key;
    }
    __syncthreads();
    for (unsigned k = 2; k <= SORTN; k <<= 1) {
        for (unsigned j = k >> 1; j > 0; j >>= 1) {
            for (unsigned i = tid; i < SORTN; i += 1024) {
                unsigned ixj = i ^ j;
                if (ixj > i) {
                    uint64_t a = keys[i], c = keys[ixj];
                    bool desc = ((i & k) == 0);
                    if (desc ? (a < c) : (a > c)) { keys[i] = c; keys[ixj] = a; }
                }
            }
            __syncthreads();
        }
    }
    for (int t = tid; t < TOPK_N; t += 1024) {
        top_idx[b * TOPK_N + t] = (int)(~(uint32_t)keys[t]);
    }
}

__global__ __launch_bounds__(1024) void nms_kernel(const float* __restrict__ pred,
                                                   const int* __restrict__ top_idx,
                                                   float* __restrict__ dets,
                                                   float* __restrict__ keep_out) {
    __shared__ uint64_t mask[TOPK_N * 16];
    __shared__ float lx1[TOPK_N], ly1[TOPK_N], lx2[TOPK_N], ly2[TOPK_N];
    __shared__ float lsc[TOPK_N], lcl[TOPK_N];
    __shared__ uint64_t removed_w[16];

    const int b = blockIdx.x;
    const int tid = threadIdx.x;
    const float* pb = pred + (size_t)b * NPRED * STRIDE;

    bool invalid = false;
    if (tid < TOPK_N) {
        int e = top_idx[b * TOPK_N + tid];
        const float* p = pb + (size_t)e * STRIDE;
        float cx = p[0], cy = p[1], w = p[2], h = p[3], obj = p[4];
        float best = p[5]; int bc = 0;
        for (int c = 1; c < NUM_CLASSES; ++c) {
            float v = p[5 + c];
            if (v > best) { best = v; bc = c; }
        }
        float w2 = __fmul_rn(w, 0.5f), h2 = __fmul_rn(h, 0.5f);
        float score = __fmul_rn(obj, best);
        lx1[tid] = __fsub_rn(cx, w2);
        ly1[tid] = __fsub_rn(cy, h2);
        lx2[tid] = __fadd_rn(cx, w2);
        ly2[tid] = __fadd_rn(cy, h2);
        lsc[tid] = score;
        lcl[tid] = (float)bc;
        invalid = (score < CONF_T);
    }
    {
        uint64_t bal = __ballot(invalid);
        if ((tid & 63) == 0) removed_w[tid >> 6] = bal;
    }
    __syncthreads();

    for (int p = tid; p < TOPK_N * 16; p += 1024) {
        int i = p >> 4, w = p & 15;
        float ci = lcl[i];
        float offi = __fmul_rn(ci, 10.0f);
        float ax1 = __fadd_rn(lx1[i], offi), ay1 = __fadd_rn(ly1[i], offi);
        float ax2 = __fadd_rn(lx2[i], offi), ay2 = __fadd_rn(ly2[i], offi);
        float areai = __fmul_rn(__fsub_rn(ax2, ax1), __fsub_rn(ay2, ay1));
        uint64_t bits = 0;
        int jend = min(TOPK_N - w * 64, 64);
        for (int bb = 0; bb < jend; ++bb) {
            int j = w * 64 + bb;
            if (j <= i) continue;
            if (lcl[j] != ci) continue;
            float bx1 = __fadd_rn(lx1[j], offi), by1 = __fadd_rn(ly1[j], offi);
            float bx2 = __fadd_rn(lx2[j], offi), by2 = __fadd_rn(ly2[j], offi);
            float areaj = __fmul_rn(__fsub_rn(bx2, bx1), __fsub_rn(by2, by1));
            float ix1 = fmaxf(ax1, bx1), iy1 = fmaxf(ay1, by1);
            float ix2 = fminf(ax2, bx2), iy2 = fminf(ay2, by2);
            float dx = fmaxf(__fsub_rn(ix2, ix1), 0.0f);
            float dy = fmaxf(__fsub_rn(iy2, iy1), 0.0f);
            float inter = __fmul_rn(dx, dy);
            float uni = __fsub_rn(__fadd_rn(areai, areaj), inter);
            float iou = __fdiv_rn(inter, fmaxf(uni, 1e-9f));
            if (iou > NMS_T) bits |= (1ull << bb);
        }
        mask[i * 16 + w] = bits;
    }
    __syncthreads();

    if (tid < 64) {
        int lane = tid;
        uint64_t rem = (lane < 16) ? removed_w[lane] : 0;
        for (int i = 0; i < TOPK_N; ++i) {
            uint64_t rw = __shfl(rem, i >> 6);
            bool alive = ((rw >> (i & 63)) & 1ull) == 0;
            uint64_t m = mask[i * 16 + (lane & 15)];
            if (alive && lane < 16) rem |= m;
        }
        if (lane < 16) removed_w[lane] = rem;
    }
    __syncthreads();

    for (int t = tid; t < TOPK_N; t += 1024) {
        bool kept = ((removed_w[t >> 6] >> (t & 63)) & 1ull) == 0;
        float* dr = dets + ((size_t)b * TOPK_N + t) * 6;
        if (kept) {
            dr[0] = lx1[t]; dr[1] = ly1[t]; dr[2] = lx2[t]; dr[3] = ly2[t];
            dr[4] = lsc[t]; dr[5] = lcl[t];
        } else {
            dr[0] = 0.0f; dr[1] = 0.0f; dr[2] = 0.0f;
            dr[3] = 0.0f; dr[4] = 0.0f; dr[5] = 0.0f;
        }
        keep_out[b * TOPK_N + t] = kept ? 1.0f : 0.0f;
    }
}

extern "C" void kernel_launch(void* const* d_in, const int* in_sizes, int n_in,
                              void* d_out, int out_size, void* d_ws, size_t ws_size,
                              hipStream_t stream) {
    const float* pred = (const float*)d_in[0];
    float* dets = (float*)d_out;                              // 32*1000*6
    float* keep = (float*)d_out + (size_t)NBATCH * TOPK_N * 6;

    const size_t total_rows = (size_t)NBATCH * NPRED;         // 268800
    const size_t keys_bytes = total_rows * sizeof(uint64_t);  // 2,150,400
    const size_t recs_bytes = total_rows * REC_F * sizeof(float); // 8,601,600
    const size_t idx_bytes  = (size_t)NBATCH * TOPK_N * sizeof(int); // 128,000

    if (ws_size >= keys_bytes + recs_bytes + idx_bytes) {
        uint64_t* keys = (uint64_t*)d_ws;
        float* recs    = (float*)((char*)d_ws + keys_bytes);
        int* top_idx   = (int*)((char*)d_ws + keys_bytes + recs_bytes);

        decode_kernel<<<(int)(total_rows / ROWS_PB), 256, 0, stream>>>(pred, keys, recs);
        select2_kernel<<<NBATCH, 1024, 0, stream>>>(keys, top_idx);
        nms2_kernel<<<NBATCH, 1024, 0, stream>>>(recs, top_idx, dets, keep);
    } else {
        int* top_idx = (int*)d_ws;
        topk_kernel<<<NBATCH, 1024, 0, stream>>>(pred, top_idx);
        nms_kernel<<<NBATCH, 1024, 0, stream>>>(pred, top_idx, dets, keep);
    }
}

// Round 14
// 67.351 us; speedup vs baseline: 2.6514x; 1.2318x over previous
//
#include <hip/hip_runtime.h>
#include <cstdint>

#define NUM_CLASSES 80
#define NPRED 8400
#define NBATCH 32
#define TOPK_N 1000
#define SORTN 16384
#define CONF_T 0.25f
#define NMS_T 0.45f
#define STRIDE 85

#define ROWS_PB 128
#define FLOATS_PB (ROWS_PB * STRIDE)   // 10880
#define F4_PB (FLOATS_PB / 4)          // 2720
#define REC_F 8                        // floats per record (padded to 32B)
#define MPAD 1026                      // lmask row stride in words (bank skew, even)
#define KREG 9                         // ceil(8400/1024) keys per thread in registers

// fused3 LDS pool layout (64-bit words):
//   select phase: hist (u32 x4096) [0,2048) | sortbuf [2048,3072)
//   mask phase:   lmask 16xMPAD [0,16416) | bx float4[1000] [16416,18416) | clsbm [18416,19696)
#define POOLW 19696                    // 157,568 bytes

__device__ __forceinline__ uint32_t f32_sortable(float f) {
    uint32_t u = __float_as_uint(f);
    return u ^ ((u >> 31) ? 0xFFFFFFFFu : 0x80000000u);
}

__device__ __forceinline__ uint64_t shfl_xor_u64(uint64_t x, int m) {
    uint32_t lo = (uint32_t)x, hi = (uint32_t)(x >> 32);
    lo = (uint32_t)__shfl_xor((int)lo, m);
    hi = (uint32_t)__shfl_xor((int)hi, m);
    return ((uint64_t)hi << 32) | lo;
}

// 46-bit key: (sortable(masked_score) << 14) | (16383 - e).
// Descending key order == descending score, ascending index on ties (lax.top_k).
__device__ __forceinline__ uint64_t decode_row(const float* p, int e,
                                               float4* rec0, float4* rec1) {
    float cx = p[0], cy = p[1], w = p[2], h = p[3], obj = p[4];
    float best = p[5]; int bc = 0;
    #pragma unroll
    for (int c = 1; c < NUM_CLASSES; ++c) {
        float v = p[5 + c];
        if (v > best) { best = v; bc = c; }        // first-max wins, like jnp.argmax
    }
    float w2 = __fmul_rn(w, 0.5f), h2 = __fmul_rn(h, 0.5f);
    float score = __fmul_rn(obj, best);
    float masked = (score >= CONF_T) ? score : -1.0f;
    *rec0 = make_float4(__fsub_rn(cx, w2), __fsub_rn(cy, h2),
                        __fadd_rn(cx, w2), __fadd_rn(cy, h2));
    *rec1 = make_float4(score, (float)bc, 0.0f, 0.0f);
    return ((uint64_t)f32_sortable(masked) << 14) | (uint32_t)(16383 - e);
}

// Full-grid decode (2100 x 256): coalesced staging, decode, write keys + recs.
__global__ __launch_bounds__(256) void decode_kernel(const float* __restrict__ pred,
                                                     uint64_t* __restrict__ keys,
                                                     float* __restrict__ recs) {
    __shared__ float s[FLOATS_PB];                 // 42.5 KiB
    const int blk = blockIdx.x;
    const int tid = threadIdx.x;
    const float4* g4 = (const float4*)pred + (size_t)blk * F4_PB;
    float4* s4 = (float4*)s;
    for (int i = tid; i < F4_PB; i += 256) s4[i] = g4[i];
    __syncthreads();
    if (tid < ROWS_PB) {
        int r = blk * ROWS_PB + tid;
        int e = r % NPRED;
        float4 rc0, rc1;
        uint64_t key = decode_row(s + tid * STRIDE, e, &rc0, &rc1);
        keys[r] = key;
        float4* rp = (float4*)(recs + (size_t)r * REC_F);
        rp[0] = rc0; rp[1] = rc1;
    }
}

// One block per batch, fully fused:
//  select: keys in 9 registers; pass-1 hist in-kernel (invalid-ballot bulk-add);
//          passes 2-4 sweep registers; wave-aggregated compaction; hybrid bitonic.
//  gather: records once; float4-packed offset boxes + class bitmaps in LDS.
//  mask:   sparse IoU (class-bitmap ctz), 1 b128 load per pair, area recomputed;
//          per-row any-bits ballot -> nzb[16] (rows that suppress anything).
//  scan:   nzb-driven (skip all-zero rows, provably a no-op), 8-wide batched
//          LDS preload + pure-VALU chain.
__global__ __launch_bounds__(1024, 1) void fused3_kernel(const uint64_t* __restrict__ keys,
                                                         const float* __restrict__ recs,
                                                         float* __restrict__ dets,
                                                         float* __restrict__ keep_out) {
    __shared__ uint64_t pool[POOLW];               // 157,568 B, phase-aliased
    __shared__ uint64_t removed_w[16];
    __shared__ uint64_t nzb_s[16];
    __shared__ uint32_t wtot[16];
    __shared__ uint32_t sh_rem, sh_cnt, sh_inv;
    __shared__ uint64_t sh_prefix;

    const int b = blockIdx.x;
    const int tid = threadIdx.x;
    const int lane = tid & 63, wid = tid >> 6;
    const uint32_t INV_HI = f32_sortable(-1.0f);   // 0x407FFFFF; invalid bin = 257

    // ---------------- select phase ----------------
    uint32_t* hist = (uint32_t*)pool;              // 4096 u32
    uint64_t* sortbuf = pool + 2048;               // 1024 words

    if (tid == 0) { sh_rem = TOPK_N; sh_cnt = 0; sh_inv = 0; sh_prefix = 0; }
    sortbuf[tid] = 0;                              // pads sink
    #pragma unroll
    for (int i = 0; i < 4; ++i) hist[tid * 4 + i] = 0;

    uint64_t kreg[KREG];
    uint32_t invw = 0;
    #pragma unroll
    for (int i = 0; i < KREG; ++i) {
        int e = i * 1024 + tid;
        uint64_t k = (e < NPRED) ? keys[(size_t)b * NPRED + e] : 0;  // pad: high bits 0
        kreg[i] = k;
        uint64_t bal = __ballot((uint32_t)(k >> 14) == INV_HI);
        if (lane == 0) invw += (uint32_t)__popcll(bal);
    }
    if (lane == 0 && invw) atomicAdd(&sh_inv, invw);
    __syncthreads();

    #pragma unroll
    for (int i = 0; i < KREG; ++i) {               // pass-1 hist over valid keys
        uint64_t k = kreg[i];
        uint32_t hi = (uint32_t)(k >> 14);
        if (hi != 0 && hi != INV_HI)
            atomicAdd(&hist[(uint32_t)(k >> 36)], 1u);
    }
    __syncthreads();

    {   // pass 1: suffix scan, 1 bin/thread; invalids folded into bin 257
        uint32_t hmine = hist[tid] + ((tid == (int)(INV_HI >> 22)) ? sh_inv : 0u);
        uint32_t v = hmine;
        #pragma unroll
        for (int off = 1; off < 64; off <<= 1) {
            uint32_t u = __shfl_down(v, off);
            if (lane + off < 64) v += u;
        }
        if (lane == 0) wtot[wid] = v;
        __syncthreads();
        uint32_t carry = 0;
        for (int w = wid + 1; w < 16; ++w) carry += wtot[w];
        uint32_t S0 = v + carry;
        if (S0 >= TOPK_N && S0 - hmine < TOPK_N) {
            sh_prefix = (uint64_t)(uint32_t)tid << 36;
            sh_rem = TOPK_N - (S0 - hmine);
        }
        __syncthreads();
    }

    for (int shift = 24; shift >= 0; shift -= 12) {   // passes 2-4 over registers
        #pragma unroll
        for (int i = 0; i < 4; ++i) hist[tid * 4 + i] = 0;
        __syncthreads();
        const uint64_t himask = ~0ull << (shift + 12);
        const uint64_t pref = sh_prefix;
        const uint32_t rem = sh_rem;
        #pragma unroll
        for (int i = 0; i < KREG; ++i) {
            uint64_t k = kreg[i];
            if ((k & himask) == (pref & himask))
                atomicAdd(&hist[(uint32_t)(k >> shift) & 4095u], 1u);
        }
        __syncthreads();
        uint32_t h0 = hist[tid * 4 + 0], h1 = hist[tid * 4 + 1];
        uint32_t h2 = hist[tid * 4 + 2], h3 = hist[tid * 4 + 3];
        uint32_t s4 = h0 + h1 + h2 + h3;
        uint32_t v = s4;
        #pragma unroll
        for (int off = 1; off < 64; off <<= 1) {
            uint32_t u = __shfl_down(v, off);
            if (lane + off < 64) v += u;
        }
        if (lane == 0) wtot[wid] = v;
        __syncthreads();
        uint32_t carry = 0;
        for (int w = wid + 1; w < 16; ++w) carry += wtot[w];
        uint32_t S0 = v + carry;
        uint32_t carry_after = S0 - s4;
        if (carry_after < rem && S0 >= rem) {
            uint32_t hh[4] = {h0, h1, h2, h3};
            uint32_t pre = 0, bestS = S0, besth = h0;
            int besti = 0;
            #pragma unroll
            for (int i = 0; i < 4; ++i) {
                uint32_t Si = S0 - pre;
                if (Si >= rem) { besti = i; bestS = Si; besth = hh[i]; }
                pre += hh[i];
            }
            sh_prefix = pref | ((uint64_t)(uint32_t)(tid * 4 + besti) << shift);
            sh_rem = rem - (bestS - besth);
        }
        __syncthreads();
    }

    const uint64_t T = sh_prefix;                  // exactly 1000 keys >= T
    #pragma unroll
    for (int i = 0; i < KREG; ++i) {
        uint64_t k = kreg[i];
        bool pr = (k >= T);
        uint64_t bal = __ballot(pr);
        uint32_t base = 0;
        if (lane == 0 && bal) base = atomicAdd(&sh_cnt, (uint32_t)__popcll(bal));
        base = __shfl(base, 0);
        if (pr) {
            uint32_t pos = base + (uint32_t)__popcll(bal & ((1ull << lane) - 1ull));
            if (pos < 1024) sortbuf[pos] = k;
        }
    }
    __syncthreads();

    uint64_t v64 = sortbuf[tid];                   // hybrid bitonic, descending
    for (unsigned k = 2; k <= 1024; k <<= 1) {
        for (unsigned j = k >> 1; j > 0; j >>= 1) {
            uint64_t o;
            if (j >= 64) {
                __syncthreads();
                sortbuf[tid] = v64;
                __syncthreads();
                o = sortbuf[tid ^ j];
            } else {
                o = shfl_xor_u64(v64, (int)j);
            }
            bool lower = (tid & j) == 0;
            bool desc = (tid & k) == 0;
            v64 = (lower == desc) ? (v64 > o ? v64 : o) : (v64 < o ? v64 : o);
        }
    }

    // ---------------- gather phase ----------------
    uint64_t* lmask = pool;                        // [0, 16416)
    float4* bx4 = (float4*)(pool + 16416);         // 1000 x float4 (offset boxes)
    uint64_t* clsbm = pool + 18416;                // 16 x 80

    float4 r0 = make_float4(0, 0, 0, 0), r1 = make_float4(0, 0, 0, 0);
    bool invalid = false;
    if (tid < TOPK_N) {
        int e = 16383 - (int)((uint32_t)v64 & 16383u);
        const float4* rp = (const float4*)(recs + ((size_t)b * NPRED + e) * REC_F);
        r0 = rp[0]; r1 = rp[1];
        invalid = (r1.x < CONF_T);
    }
    {
        uint64_t bal = __ballot(invalid);
        if ((tid & 63) == 0) removed_w[tid >> 6] = bal;
    }
    for (int i = tid; i < 16 * NUM_CLASSES; i += 1024) clsbm[i] = 0;  // no alias w/ sortbuf
    __syncthreads();                               // select-era LDS reads retired

    float ax1 = 0, ay1 = 0, ax2 = 0, ay2 = 0, areai = 0;
    int mycls = 0;
    if (tid < TOPK_N) {
        float offv = __fmul_rn(r1.y, 10.0f);       // exact: class*10 <= 790
        ax1 = __fadd_rn(r0.x, offv); ay1 = __fadd_rn(r0.y, offv);
        ax2 = __fadd_rn(r0.z, offv); ay2 = __fadd_rn(r0.w, offv);
        areai = __fmul_rn(__fsub_rn(ax2, ax1), __fsub_rn(ay2, ay1));
        mycls = (int)r1.y;
        bx4[tid] = make_float4(ax1, ay1, ax2, ay2);
        atomicOr(&clsbm[(tid >> 6) * NUM_CLASSES + mycls], 1ull << (tid & 63));
    }
    __syncthreads();

    // ---------------- mask phase ----------------
    const int myw = tid >> 6;
    uint64_t anyb = 0;
    if (tid < TOPK_N) {
        for (int w = 0; w < 16; ++w) {
            uint64_t bits = 0;
            if (w >= myw) {
                uint64_t bm = clsbm[w * NUM_CLASSES + mycls];
                if (w == myw) bm &= ~((2ull << (tid & 63)) - 1ull);  // j > tid only
                while (bm) {
                    int bb = __builtin_ctzll(bm);
                    bm &= bm - 1;
                    int j = w * 64 + bb;
                    float4 bj = bx4[j];            // one b128 load per candidate
                    float areaj = __fmul_rn(__fsub_rn(bj.z, bj.x), __fsub_rn(bj.w, bj.y));
                    float ix1 = fmaxf(ax1, bj.x), iy1 = fmaxf(ay1, bj.y);
                    float ix2 = fminf(ax2, bj.z), iy2 = fminf(ay2, bj.w);
                    float dx = fmaxf(__fsub_rn(ix2, ix1), 0.0f);
                    float dy = fmaxf(__fsub_rn(iy2, iy1), 0.0f);
                    float inter = __fmul_rn(dx, dy);
                    float uni = __fsub_rn(__fadd_rn(areai, areaj), inter);
                    float iou = __fdiv_rn(inter, fmaxf(uni, 1e-9f));
                    if (iou > NMS_T) bits |= (1ull << bb);
                }
            }
            lmask[w * MPAD + tid] = bits;          // lane-consecutive -> conflict-free
            anyb |= bits;
        }
    } else {
        #pragma unroll
        for (int w = 0; w < 16; ++w) lmask[w * MPAD + tid] = 0;  // phantom rows
    }
    {   // nzb[w] bit bb = row w*64+bb suppresses something (wave w == rows w*64..)
        uint64_t nzw = __ballot(anyb != 0);
        if ((tid & 63) == 0) nzb_s[tid >> 6] = nzw;
    }
    __syncthreads();

    // ---------------- scan phase (nzb-driven) ----------------
    // All-zero rows are exact no-ops (cur|=0, rem|=0 whether alive or dead),
    // so iterate only rows flagged in nzb. 8-wide batches: ctz extraction,
    // static-index register preload, then the dependent VALU chain.
    if (tid < 64) {
        const int l = tid & 15;
        uint64_t rem = (tid < 16) ? removed_w[tid] : 0;
        for (int W = 0; W < 16; ++W) {
            uint64_t cur = __shfl(rem, W);         // word W incl. earlier suppressions
            uint64_t nz = nzb_s[W];                // broadcast, wave-uniform
            const int base = W * 64;
            while (nz) {
                int bbs[8];
                #pragma unroll
                for (int q = 0; q < 8; ++q) {      // ascending-bit extraction
                    bbs[q] = nz ? (int)__builtin_ctzll(nz) : -1;
                    nz &= nz - 1;                  // 0 stays 0
                }
                uint64_t mWv[8], mlv[8];
                #pragma unroll
                for (int q = 0; q < 8; ++q) {
                    int i = base + (bbs[q] >= 0 ? bbs[q] : 0);
                    mWv[q] = lmask[W * MPAD + i];  // broadcast read
                    mlv[q] = lmask[l * MPAD + i];  // own-row read
                }
                #pragma unroll
                for (int q = 0; q < 8; ++q) {
                    if (bbs[q] >= 0) {             // wave-uniform condition
                        uint64_t sel = ((cur >> bbs[q]) & 1ull) ? 0ull : ~0ull;
                        cur |= (mWv[q] & sel);     // mask row has no bits <= bb
                        rem |= (mlv[q] & sel);
                    }
                }
            }
        }
        if (tid < 16) removed_w[tid] = rem;
    }
    __syncthreads();

    if (tid < TOPK_N) {
        bool kept = ((removed_w[tid >> 6] >> (tid & 63)) & 1ull) == 0;
        float* dr = dets + ((size_t)b * TOPK_N + tid) * 6;
        if (kept) {
            dr[0] = r0.x; dr[1] = r0.y; dr[2] = r0.z; dr[3] = r0.w;
            dr[4] = r1.x; dr[5] = r1.y;
        } else {
            dr[0] = 0.0f; dr[1] = 0.0f; dr[2] = 0.0f;
            dr[3] = 0.0f; dr[4] = 0.0f; dr[5] = 0.0f;
        }
        keep_out[b * TOPK_N + tid] = kept ? 1.0f : 0.0f;
    }
}

// ---------- fallback kernels (small ws): r1 path ----------

__global__ __launch_bounds__(1024) void topk_kernel(const float* __restrict__ pred,
                                                    int* __restrict__ top_idx) {
    __shared__ uint64_t keys[SORTN];
    const int b = blockIdx.x;
    const int tid = threadIdx.x;
    const float* pb = pred + (size_t)b * NPRED * STRIDE;

    for (int e = tid; e < SORTN; e += 1024) {
        uint64_t key = 0;
        if (e < NPRED) {
            const float* p = pb + (size_t)e * STRIDE;
            float obj = p[4];
            float best = p[5];
            #pragma unroll 8
            for (int c = 1; c < NUM_CLASSES; ++c) best = fmaxf(best, p[5 + c]);
            float score = __fmul_rn(obj, best);
            float masked = (score >= CONF_T) ? score : -1.0f;
            key = ((uint64_t)f32_sortable(masked) << 32) | (uint32_t)(~(uint32_t)e);
        }
        keys[e] = key;
    }
    __syncthreads();
    for (unsigned k = 2; k <= SORTN; k <<= 1) {
        for (unsigned j = k >> 1; j > 0; j >>= 1) {
            for (unsigned i = tid; i < SORTN; i += 1024) {
                unsigned ixj = i ^ j;
                if (ixj > i) {
                    uint64_t a = keys[i], c = keys[ixj];
                    bool desc = ((i & k) == 0);
                    if (desc ? (a < c) : (a > c)) { keys[i] = c; keys[ixj] = a; }
                }
            }
            __syncthreads();
        }
    }
    for (int t = tid; t < TOPK_N; t += 1024) {
        top_idx[b * TOPK_N + t] = (int)(~(uint32_t)keys[t]);
    }
}

__global__ __launch_bounds__(1024) void nms_kernel(const float* __restrict__ pred,
                                                   const int* __restrict__ top_idx,
                                                   float* __restrict__ dets,
                                                   float* __restrict__ keep_out) {
    __shared__ uint64_t mask[TOPK_N * 16];
    __shared__ float lx1[TOPK_N], ly1[TOPK_N], lx2[TOPK_N], ly2[TOPK_N];
    __shared__ float lsc[TOPK_N], lcl[TOPK_N];
    __shared__ uint64_t removed_w[16];

    const int b = blockIdx.x;
    const int tid = threadIdx.x;
    const float* pb = pred + (size_t)b * NPRED * STRIDE;

    bool invalid = false;
    if (tid < TOPK_N) {
        int e = top_idx[b * TOPK_N + tid];
        const float* p = pb + (size_t)e * STRIDE;
        float cx = p[0], cy = p[1], w = p[2], h = p[3], obj = p[4];
        float best = p[5]; int bc = 0;
        for (int c = 1; c < NUM_CLASSES; ++c) {
            float v = p[5 + c];
            if (v > best) { best = v; bc = c; }
        }
        float w2 = __fmul_rn(w, 0.5f), h2 = __fmul_rn(h, 0.5f);
        float score = __fmul_rn(obj, best);
        lx1[tid] = __fsub_rn(cx, w2);
        ly1[tid] = __fsub_rn(cy, h2);
        lx2[tid] = __fadd_rn(cx, w2);
        ly2[tid] = __fadd_rn(cy, h2);
        lsc[tid] = score;
        lcl[tid] = (float)bc;
        invalid = (score < CONF_T);
    }
    {
        uint64_t bal = __ballot(invalid);
        if ((tid & 63) == 0) removed_w[tid >> 6] = bal;
    }
    __syncthreads();

    for (int p = tid; p < TOPK_N * 16; p += 1024) {
        int i = p >> 4, w = p & 15;
        float ci = lcl[i];
        float offi = __fmul_rn(ci, 10.0f);
        float ax1 = __fadd_rn(lx1[i], offi), ay1 = __fadd_rn(ly1[i], offi);
        float ax2 = __fadd_rn(lx2[i], offi), ay2 = __fadd_rn(ly2[i], offi);
        float areai = __fmul_rn(__fsub_rn(ax2, ax1), __fsub_rn(ay2, ay1));
        uint64_t bits = 0;
        int jend = min(TOPK_N - w * 64, 64);
        for (int bb = 0; bb < jend; ++bb) {
            int j = w * 64 + bb;
            if (j <= i) continue;
            if (lcl[j] != ci) continue;
            float bx1 = __fadd_rn(lx1[j], offi), by1 = __fadd_rn(ly1[j], offi);
            float bx2 = __fadd_rn(lx2[j], offi), by2 = __fadd_rn(ly2[j], offi);
            float areaj = __fmul_rn(__fsub_rn(bx2, bx1), __fsub_rn(by2, by1));
            float ix1 = fmaxf(ax1, bx1), iy1 = fmaxf(ay1, by1);
            float ix2 = fminf(ax2, bx2), iy2 = fminf(ay2, by2);
            float dx = fmaxf(__fsub_rn(ix2, ix1), 0.0f);
            float dy = fmaxf(__fsub_rn(iy2, iy1), 0.0f);
            float inter = __fmul_rn(dx, dy);
            float uni = __fsub_rn(__fadd_rn(areai, areaj), inter);
            float iou = __fdiv_rn(inter, fmaxf(uni, 1e-9f));
            if (iou > NMS_T) bits |= (1ull << bb);
        }
        mask[i * 16 + w] = bits;
    }
    __syncthreads();

    if (tid < 64) {
        int lane = tid;
        uint64_t rem = (lane < 16) ? removed_w[lane] : 0;
        for (int i = 0; i < TOPK_N; ++i) {
            uint64_t rw = __shfl(rem, i >> 6);
            bool alive = ((rw >> (i & 63)) & 1ull) == 0;
            uint64_t m = mask[i * 16 + (lane & 15)];
            if (alive && lane < 16) rem |= m;
        }
        if (lane < 16) removed_w[lane] = rem;
    }
    __syncthreads();

    for (int t = tid; t < TOPK_N; t += 1024) {
        bool kept = ((removed_w[t >> 6] >> (t & 63)) & 1ull) == 0;
        float* dr = dets + ((size_t)b * TOPK_N + t) * 6;
        if (kept) {
            dr[0] = lx1[t]; dr[1] = ly1[t]; dr[2] = lx2[t]; dr[3] = ly2[t];
            dr[4] = lsc[t]; dr[5] = lcl[t];
        } else {
            dr[0] = 0.0f; dr[1] = 0.0f; dr[2] = 0.0f;
            dr[3] = 0.0f; dr[4] = 0.0f; dr[5] = 0.0f;
        }
        keep_out[b * TOPK_N + t] = kept ? 1.0f : 0.0f;
    }
}

extern "C" void kernel_launch(void* const* d_in, const int* in_sizes, int n_in,
                              void* d_out, int out_size, void* d_ws, size_t ws_size,
                              hipStream_t stream) {
    const float* pred = (const float*)d_in[0];
    float* dets = (float*)d_out;                              // 32*1000*6
    float* keep = (float*)d_out + (size_t)NBATCH * TOPK_N * 6;

    const size_t total_rows = (size_t)NBATCH * NPRED;         // 268800
    const size_t keys_bytes = total_rows * sizeof(uint64_t);  // 2,150,400
    const size_t recs_bytes = total_rows * REC_F * sizeof(float); // 8,601,600

    if (ws_size >= keys_bytes + recs_bytes) {
        uint64_t* keys = (uint64_t*)d_ws;
        float* recs    = (float*)((char*)d_ws + keys_bytes);

        decode_kernel<<<(int)(total_rows / ROWS_PB), 256, 0, stream>>>(pred, keys, recs);
        fused3_kernel<<<NBATCH, 1024, 0, stream>>>(keys, recs, dets, keep);
    } else {
        int* top_idx = (int*)d_ws;
        topk_kernel<<<NBATCH, 1024, 0, stream>>>(pred, top_idx);
        nms_kernel<<<NBATCH, 1024, 0, stream>>>(pred, top_idx, dets, keep);
    }
}

// Round 15
// 65.319 us; speedup vs baseline: 2.7339x; 1.0311x over previous
//
#include <hip/hip_runtime.h>
#include <cstdint>

#define NUM_CLASSES 80
#define NPRED 8400
#define NBATCH 32
#define TOPK_N 1000
#define SORTN 16384
#define CONF_T 0.25f
#define NMS_T 0.45f
#define STRIDE 85

#define ROWS_PB 128
#define FLOATS_PB (ROWS_PB * STRIDE)   // 10880
#define F4_PB (FLOATS_PB / 4)          // 2720
#define REC_F 8                        // floats per record (padded to 32B)
#define MPAD 1026                      // lmask row stride in words (bank skew, even)
#define KREG 9                         // ceil(8400/1024) keys per thread in registers

// fused4 LDS pool layout (64-bit words):
//   select phase: hist (u32 x4096) [0,2048) | sortbuf [2048,3072)
//   mask phase:   lmask 16xMPAD [0,16416) | bx float4[1000] [16416,18416) | clsbm [18416,19696)
#define POOLW 19696                    // 157,568 bytes

__device__ __forceinline__ uint32_t f32_sortable(float f) {
    uint32_t u = __float_as_uint(f);
    return u ^ ((u >> 31) ? 0xFFFFFFFFu : 0x80000000u);
}

__device__ __forceinline__ uint64_t shfl_xor_u64(uint64_t x, int m) {
    uint32_t lo = (uint32_t)x, hi = (uint32_t)(x >> 32);
    lo = (uint32_t)__shfl_xor((int)lo, m);
    hi = (uint32_t)__shfl_xor((int)hi, m);
    return ((uint64_t)hi << 32) | lo;
}

// 46-bit key (reconstructed in-register): (sortable(masked_score) << 14) | (16383 - e).
// Descending key order == descending score, ascending index on ties (lax.top_k).
__device__ __forceinline__ uint32_t decode_row32(const float* p, float4* rec0, float4* rec1) {
    float cx = p[0], cy = p[1], w = p[2], h = p[3], obj = p[4];
    float best = p[5]; int bc = 0;
    #pragma unroll
    for (int c = 1; c < NUM_CLASSES; ++c) {
        float v = p[5 + c];
        if (v > best) { best = v; bc = c; }        // first-max wins, like jnp.argmax
    }
    float w2 = __fmul_rn(w, 0.5f), h2 = __fmul_rn(h, 0.5f);
    float score = __fmul_rn(obj, best);
    float masked = (score >= CONF_T) ? score : -1.0f;
    *rec0 = make_float4(__fsub_rn(cx, w2), __fsub_rn(cy, h2),
                        __fadd_rn(cx, w2), __fadd_rn(cy, h2));
    *rec1 = make_float4(score, (float)bc, 0.0f, 0.0f);
    return f32_sortable(masked);
}

// Full-grid decode (2100 x 256): coalesced staging, decode, write u32 score-keys + recs.
__global__ __launch_bounds__(256) void decode_kernel(const float* __restrict__ pred,
                                                     uint32_t* __restrict__ keys32,
                                                     float* __restrict__ recs) {
    __shared__ float s[FLOATS_PB];                 // 42.5 KiB
    const int blk = blockIdx.x;
    const int tid = threadIdx.x;
    const float4* g4 = (const float4*)pred + (size_t)blk * F4_PB;
    float4* s4 = (float4*)s;
    for (int i = tid; i < F4_PB; i += 256) s4[i] = g4[i];
    __syncthreads();
    if (tid < ROWS_PB) {
        int r = blk * ROWS_PB + tid;
        float4 rc0, rc1;
        uint32_t s32 = decode_row32(s + tid * STRIDE, &rc0, &rc1);
        keys32[r] = s32;
        float4* rp = (float4*)(recs + (size_t)r * REC_F);
        rp[0] = rc0; rp[1] = rc1;
    }
}

// One block per batch, fully fused (r14 structure + 3-pass select):
//  select: u32 keys -> 64-bit keys in 9 registers; pass-1 hist (invalid-ballot
//          bulk-add); 2 register sweeps (bits 35:24, 23:12); superset winners
//          (k >= 34-bit bin floor, <=1024 total; exact pass-4 fallback if not);
//          wave-aggregated compaction; hybrid bitonic (first 1000 = exact top_k).
//  gather: records once; float4-packed offset boxes + class bitmaps in LDS.
//  mask:   sparse IoU via class-bitmap ctz, 1 b128 load per pair; nzb ballot.
//  scan:   nzb-driven batched scan (skip all-zero rows).
__global__ __launch_bounds__(1024, 1) void fused4_kernel(const uint32_t* __restrict__ keys32,
                                                         const float* __restrict__ recs,
                                                         float* __restrict__ dets,
                                                         float* __restrict__ keep_out) {
    __shared__ uint64_t pool[POOLW];               // 157,568 B, phase-aliased
    __shared__ uint64_t removed_w[16];
    __shared__ uint64_t nzb_s[16];
    __shared__ uint32_t wtot[16];
    __shared__ uint32_t sh_rem, sh_cnt, sh_inv, sh_need4;
    __shared__ uint64_t sh_prefix;

    const int b = blockIdx.x;
    const int tid = threadIdx.x;
    const int lane = tid & 63, wid = tid >> 6;
    const uint32_t INV_S32 = f32_sortable(-1.0f);  // 0x407FFFFF; pass-1 bin = 257

    // ---------------- select phase ----------------
    uint32_t* hist = (uint32_t*)pool;              // 4096 u32
    uint64_t* sortbuf = pool + 2048;               // 1024 words

    if (tid == 0) { sh_rem = TOPK_N; sh_cnt = 0; sh_inv = 0; sh_need4 = 0; sh_prefix = 0; }
    sortbuf[tid] = 0;                              // pads sink
    #pragma unroll
    for (int i = 0; i < 4; ++i) hist[tid * 4 + i] = 0;

    uint64_t kreg[KREG];
    uint32_t invw = 0;
    #pragma unroll
    for (int i = 0; i < KREG; ++i) {
        int e = i * 1024 + tid;
        uint64_t k = 0;
        if (e < NPRED) {
            uint32_t s32 = keys32[(size_t)b * NPRED + e];
            k = ((uint64_t)s32 << 14) | (uint32_t)(16383 - e);
        }
        kreg[i] = k;                               // pad: 0 (never selected)
        uint64_t bal = __ballot((uint32_t)(k >> 14) == INV_S32);
        if (lane == 0) invw += (uint32_t)__popcll(bal);
    }
    if (lane == 0 && invw) atomicAdd(&sh_inv, invw);
    __syncthreads();

    #pragma unroll
    for (int i = 0; i < KREG; ++i) {               // pass-1 hist over valid keys
        uint64_t k = kreg[i];
        uint32_t hi = (uint32_t)(k >> 14);
        if (hi != 0 && hi != INV_S32)
            atomicAdd(&hist[(uint32_t)(k >> 36)], 1u);
    }
    __syncthreads();

    {   // pass 1: suffix scan, 1 bin/thread; invalids folded into bin 257
        uint32_t hmine = hist[tid] + ((tid == (int)(INV_S32 >> 22)) ? sh_inv : 0u);
        uint32_t v = hmine;
        #pragma unroll
        for (int off = 1; off < 64; off <<= 1) {
            uint32_t u = __shfl_down(v, off);
            if (lane + off < 64) v += u;
        }
        if (lane == 0) wtot[wid] = v;
        __syncthreads();
        uint32_t carry = 0;
        for (int w = wid + 1; w < 16; ++w) carry += wtot[w];
        uint32_t S0 = v + carry;
        if (S0 >= TOPK_N && S0 - hmine < TOPK_N) {
            sh_prefix = (uint64_t)(uint32_t)tid << 36;
            sh_rem = TOPK_N - (S0 - hmine);
        }
        __syncthreads();
    }

    // passes 2-3 over registers (bits 35:24, 23:12); pass 3 records bin count
    // and sets need4 iff the superset would exceed the 1024-slot sort buffer.
    for (int shift = 24; shift >= 12; shift -= 12) {
        #pragma unroll
        for (int i = 0; i < 4; ++i) hist[tid * 4 + i] = 0;
        __syncthreads();
        const uint64_t himask = ~0ull << (shift + 12);
        const uint64_t pref = sh_prefix;
        const uint32_t rem = sh_rem;
        #pragma unroll
        for (int i = 0; i < KREG; ++i) {
            uint64_t k = kreg[i];
            if ((k & himask) == (pref & himask))   // pads (0) can't match: pref bin >= 257
                atomicAdd(&hist[(uint32_t)(k >> shift) & 4095u], 1u);
        }
        __syncthreads();
        uint32_t h0 = hist[tid * 4 + 0], h1 = hist[tid * 4 + 1];
        uint32_t h2 = hist[tid * 4 + 2], h3 = hist[tid * 4 + 3];
        uint32_t s4 = h0 + h1 + h2 + h3;
        uint32_t v = s4;
        #pragma unroll
        for (int off = 1; off < 64; off <<= 1) {
            uint32_t u = __shfl_down(v, off);
            if (lane + off < 64) v += u;
        }
        if (lane == 0) wtot[wid] = v;
        __syncthreads();
        uint32_t carry = 0;
        for (int w = wid + 1; w < 16; ++w) carry += wtot[w];
        uint32_t S0 = v + carry;
        uint32_t carry_after = S0 - s4;
        if (carry_after < rem && S0 >= rem) {      // exactly one thread crosses
            uint32_t hh[4] = {h0, h1, h2, h3};
            uint32_t pre = 0, bestS = S0, besth = h0;
            int besti = 0;
            #pragma unroll
            for (int i = 0; i < 4; ++i) {
                uint32_t Si = S0 - pre;
                if (Si >= rem) { besti = i; bestS = Si; besth = hh[i]; }
                pre += hh[i];
            }
            sh_prefix = pref | ((uint64_t)(uint32_t)(tid * 4 + besti) << shift);
            uint32_t newrem = rem - (bestS - besth);
            sh_rem = newrem;
            if (shift == 12) {                     // superset size = 1000 - newrem + besth
                if ((uint32_t)TOPK_N - newrem + besth > 1024u) sh_need4 = 1;
            }
        }
        __syncthreads();
    }

    if (sh_need4) {                                // exact fallback (requires >24 f32-equal
        #pragma unroll                             //  scores sharing top index bits; ~never)
        for (int i = 0; i < 4; ++i) hist[tid * 4 + i] = 0;
        __syncthreads();
        const uint64_t himask = ~0ull << 12;
        const uint64_t pref = sh_prefix;
        const uint32_t rem = sh_rem;
        #pragma unroll
        for (int i = 0; i < KREG; ++i) {
            uint64_t k = kreg[i];
            if ((k & himask) == (pref & himask))
                atomicAdd(&hist[(uint32_t)k & 4095u], 1u);
        }
        __syncthreads();
        uint32_t h0 = hist[tid * 4 + 0], h1 = hist[tid * 4 + 1];
        uint32_t h2 = hist[tid * 4 + 2], h3 = hist[tid * 4 + 3];
        uint32_t s4 = h0 + h1 + h2 + h3;
        uint32_t v = s4;
        #pragma unroll
        for (int off = 1; off < 64; off <<= 1) {
            uint32_t u = __shfl_down(v, off);
            if (lane + off < 64) v += u;
        }
        if (lane == 0) wtot[wid] = v;
        __syncthreads();
        uint32_t carry = 0;
        for (int w = wid + 1; w < 16; ++w) carry += wtot[w];
        uint32_t S0 = v + carry;
        uint32_t carry_after = S0 - s4;
        if (carry_after < rem && S0 >= rem) {
            uint32_t hh[4] = {h0, h1, h2, h3};
            uint32_t pre = 0, bestS = S0, besth = h0;
            int besti = 0;
            #pragma unroll
            for (int i = 0; i < 4; ++i) {
                uint32_t Si = S0 - pre;
                if (Si >= rem) { besti = i; bestS = Si; besth = hh[i]; }
                pre += hh[i];
            }
            sh_prefix = pref | (uint32_t)(tid * 4 + besti);
            sh_rem = rem - (bestS - besth);
        }
        __syncthreads();
    }

    // superset compaction: all keys >= T (T = bin floor or exact pass-4 prefix).
    // <=1024 winners; sorting descending makes slots [0,1000) the exact top_k.
    const uint64_t T = sh_prefix;
    #pragma unroll
    for (int i = 0; i < KREG; ++i) {
        uint64_t k = kreg[i];
        bool pr = (k >= T);                        // pads (0) always fail
        uint64_t bal = __ballot(pr);
        uint32_t base = 0;
        if (lane == 0 && bal) base = atomicAdd(&sh_cnt, (uint32_t)__popcll(bal));
        base = __shfl(base, 0);
        if (pr) {
            uint32_t pos = base + (uint32_t)__popcll(bal & ((1ull << lane) - 1ull));
            if (pos < 1024) sortbuf[pos] = k;
        }
    }
    // hoisted: zero clsbm now (no alias with sortbuf/hist regions)
    uint64_t* clsbm = pool + 18416;                // 16 x 80
    for (int i = tid; i < 16 * NUM_CLASSES; i += 1024) clsbm[i] = 0;
    __syncthreads();

    uint64_t v64 = sortbuf[tid];                   // hybrid bitonic, descending
    for (unsigned k = 2; k <= 1024; k <<= 1) {
        for (unsigned j = k >> 1; j > 0; j >>= 1) {
            uint64_t o;
            if (j >= 64) {
                __syncthreads();
                sortbuf[tid] = v64;
                __syncthreads();
                o = sortbuf[tid ^ j];
            } else {
                o = shfl_xor_u64(v64, (int)j);
            }
            bool lower = (tid & j) == 0;
            bool desc = (tid & k) == 0;
            v64 = (lower == desc) ? (v64 > o ? v64 : o) : (v64 < o ? v64 : o);
        }
    }

    // ---------------- gather phase ----------------
    uint64_t* lmask = pool;                        // [0, 16416)
    float4* bx4 = (float4*)(pool + 16416);         // 1000 x float4 (offset boxes)

    float4 r0 = make_float4(0, 0, 0, 0), r1 = make_float4(0, 0, 0, 0);
    bool invalid = false;
    if (tid < TOPK_N) {
        int e = 16383 - (int)((uint32_t)v64 & 16383u);
        const float4* rp = (const float4*)(recs + ((size_t)b * NPRED + e) * REC_F);
        r0 = rp[0]; r1 = rp[1];
        invalid = (r1.x < CONF_T);
    }
    {
        uint64_t bal = __ballot(invalid);
        if ((tid & 63) == 0) removed_w[tid >> 6] = bal;
    }
    __syncthreads();                               // select-era LDS reads retired

    float ax1 = 0, ay1 = 0, ax2 = 0, ay2 = 0, areai = 0;
    int mycls = 0;
    if (tid < TOPK_N) {
        float offv = __fmul_rn(r1.y, 10.0f);       // exact: class*10 <= 790
        ax1 = __fadd_rn(r0.x, offv); ay1 = __fadd_rn(r0.y, offv);
        ax2 = __fadd_rn(r0.z, offv); ay2 = __fadd_rn(r0.w, offv);
        areai = __fmul_rn(__fsub_rn(ax2, ax1), __fsub_rn(ay2, ay1));
        mycls = (int)r1.y;
        bx4[tid] = make_float4(ax1, ay1, ax2, ay2);
        atomicOr(&clsbm[(tid >> 6) * NUM_CLASSES + mycls], 1ull << (tid & 63));
    }
    __syncthreads();

    // ---------------- mask phase ----------------
    const int myw = tid >> 6;
    uint64_t anyb = 0;
    if (tid < TOPK_N) {
        for (int w = 0; w < 16; ++w) {
            uint64_t bits = 0;
            if (w >= myw) {
                uint64_t bm = clsbm[w * NUM_CLASSES + mycls];
                if (w == myw) bm &= ~((2ull << (tid & 63)) - 1ull);  // j > tid only
                while (bm) {
                    int bb = __builtin_ctzll(bm);
                    bm &= bm - 1;
                    int j = w * 64 + bb;
                    float4 bj = bx4[j];            // one b128 load per candidate
                    float areaj = __fmul_rn(__fsub_rn(bj.z, bj.x), __fsub_rn(bj.w, bj.y));
                    float ix1 = fmaxf(ax1, bj.x), iy1 = fmaxf(ay1, bj.y);
                    float ix2 = fminf(ax2, bj.z), iy2 = fminf(ay2, bj.w);
                    float dx = fmaxf(__fsub_rn(ix2, ix1), 0.0f);
                    float dy = fmaxf(__fsub_rn(iy2, iy1), 0.0f);
                    float inter = __fmul_rn(dx, dy);
                    float uni = __fsub_rn(__fadd_rn(areai, areaj), inter);
                    float iou = __fdiv_rn(inter, fmaxf(uni, 1e-9f));
                    if (iou > NMS_T) bits |= (1ull << bb);
                }
            }
            lmask[w * MPAD + tid] = bits;          // lane-consecutive -> conflict-free
            anyb |= bits;
        }
    } else {
        #pragma unroll
        for (int w = 0; w < 16; ++w) lmask[w * MPAD + tid] = 0;  // phantom rows
    }
    {
        uint64_t nzw = __ballot(anyb != 0);
        if ((tid & 63) == 0) nzb_s[tid >> 6] = nzw;
    }
    __syncthreads();

    // ---------------- scan phase (nzb-driven) ----------------
    if (tid < 64) {
        const int l = tid & 15;
        uint64_t rem = (tid < 16) ? removed_w[tid] : 0;
        for (int W = 0; W < 16; ++W) {
            uint64_t cur = __shfl(rem, W);
            uint64_t nz = nzb_s[W];
            const int base = W * 64;
            while (nz) {
                int bbs[8];
                #pragma unroll
                for (int q = 0; q < 8; ++q) {
                    bbs[q] = nz ? (int)__builtin_ctzll(nz) : -1;
                    nz &= nz - 1;
                }
                uint64_t mWv[8], mlv[8];
                #pragma unroll
                for (int q = 0; q < 8; ++q) {
                    int i = base + (bbs[q] >= 0 ? bbs[q] : 0);
                    mWv[q] = lmask[W * MPAD + i];
                    mlv[q] = lmask[l * MPAD + i];
                }
                #pragma unroll
                for (int q = 0; q < 8; ++q) {
                    if (bbs[q] >= 0) {
                        uint64_t sel = ((cur >> bbs[q]) & 1ull) ? 0ull : ~0ull;
                        cur |= (mWv[q] & sel);
                        rem |= (mlv[q] & sel);
                    }
                }
            }
        }
        if (tid < 16) removed_w[tid] = rem;
    }
    __syncthreads();

    if (tid < TOPK_N) {
        bool kept = ((removed_w[tid >> 6] >> (tid & 63)) & 1ull) == 0;
        float* dr = dets + ((size_t)b * TOPK_N + tid) * 6;
        if (kept) {
            dr[0] = r0.x; dr[1] = r0.y; dr[2] = r0.z; dr[3] = r0.w;
            dr[4] = r1.x; dr[5] = r1.y;
        } else {
            dr[0] = 0.0f; dr[1] = 0.0f; dr[2] = 0.0f;
            dr[3] = 0.0f; dr[4] = 0.0f; dr[5] = 0.0f;
        }
        keep_out[b * TOPK_N + tid] = kept ? 1.0f : 0.0f;
    }
}

// ---------- fallback kernels (small ws): r1 path ----------

__global__ __launch_bounds__(1024) void topk_kernel(const float* __restrict__ pred,
                                                    int* __restrict__ top_idx) {
    __shared__ uint64_t keys[SORTN];
    const int b = blockIdx.x;
    const int tid = threadIdx.x;
    const float* pb = pred + (size_t)b * NPRED * STRIDE;

    for (int e = tid; e < SORTN; e += 1024) {
        uint64_t key = 0;
        if (e < NPRED) {
            const float* p = pb + (size_t)e * STRIDE;
            float obj = p[4];
            float best = p[5];
            #pragma unroll 8
            for (int c = 1; c < NUM_CLASSES; ++c) best = fmaxf(best, p[5 + c]);
            float score = __fmul_rn(obj, best);
            float masked = (score >= CONF_T) ? score : -1.0f;
            key = ((uint64_t)f32_sortable(masked) << 32) | (uint32_t)(~(uint32_t)e);
        }
        keys[e] = key;
    }
    __syncthreads();
    for (unsigned k = 2; k <= SORTN; k <<= 1) {
        for (unsigned j = k >> 1; j > 0; j >>= 1) {
            for (unsigned i = tid; i < SORTN; i += 1024) {
                unsigned ixj = i ^ j;
                if (ixj > i) {
                    uint64_t a = keys[i], c = keys[ixj];
                    bool desc = ((i & k) == 0);
                    if (desc ? (a < c) : (a > c)) { keys[i] = c; keys[ixj] = a; }
                }
            }
            __syncthreads();
        }
    }
    for (int t = tid; t < TOPK_N; t += 1024) {
        top_idx[b * TOPK_N + t] = (int)(~(uint32_t)keys[t]);
    }
}

__global__ __launch_bounds__(1024) void nms_kernel(const float* __restrict__ pred,
                                                   const int* __restrict__ top_idx,
                                                   float* __restrict__ dets,
                                                   float* __restrict__ keep_out) {
    __shared__ uint64_t mask[TOPK_N * 16];
    __shared__ float lx1[TOPK_N], ly1[TOPK_N], lx2[TOPK_N], ly2[TOPK_N];
    __shared__ float lsc[TOPK_N], lcl[TOPK_N];
    __shared__ uint64_t removed_w[16];

    const int b = blockIdx.x;
    const int tid = threadIdx.x;
    const float* pb = pred + (size_t)b * NPRED * STRIDE;

    bool invalid = false;
    if (tid < TOPK_N) {
        int e = top_idx[b * TOPK_N + tid];
        const float* p = pb + (size_t)e * STRIDE;
        float cx = p[0], cy = p[1], w = p[2], h = p[3], obj = p[4];
        float best = p[5]; int bc = 0;
        for (int c = 1; c < NUM_CLASSES; ++c) {
            float v = p[5 + c];
            if (v > best) { best = v; bc = c; }
        }
        float w2 = __fmul_rn(w, 0.5f), h2 = __fmul_rn(h, 0.5f);
        float score = __fmul_rn(obj, best);
        lx1[tid] = __fsub_rn(cx, w2);
        ly1[tid] = __fsub_rn(cy, h2);
        lx2[tid] = __fadd_rn(cx, w2);
        ly2[tid] = __fadd_rn(cy, h2);
        lsc[tid] = score;
        lcl[tid] = (float)bc;
        invalid = (score < CONF_T);
    }
    {
        uint64_t bal = __ballot(invalid);
        if ((tid & 63) == 0) removed_w[tid >> 6] = bal;
    }
    __syncthreads();

    for (int p = tid; p < TOPK_N * 16; p += 1024) {
        int i = p >> 4, w = p & 15;
        float ci = lcl[i];
        float offi = __fmul_rn(ci, 10.0f);
        float ax1 = __fadd_rn(lx1[i], offi), ay1 = __fadd_rn(ly1[i], offi);
        float ax2 = __fadd_rn(lx2[i], offi), ay2 = __fadd_rn(ly2[i], offi);
        float areai = __fmul_rn(__fsub_rn(ax2, ax1), __fsub_rn(ay2, ay1));
        uint64_t bits = 0;
        int jend = min(TOPK_N - w * 64, 64);
        for (int bb = 0; bb < jend; ++bb) {
            int j = w * 64 + bb;
            if (j <= i) continue;
            if (lcl[j] != ci) continue;
            float bx1 = __fadd_rn(lx1[j], offi), by1 = __fadd_rn(ly1[j], offi);
            float bx2 = __fadd_rn(lx2[j], offi), by2 = __fadd_rn(ly2[j], offi);
            float areaj = __fmul_rn(__fsub_rn(bx2, bx1), __fsub_rn(by2, by1));
            float ix1 = fmaxf(ax1, bx1), iy1 = fmaxf(ay1, by1);
            float ix2 = fminf(ax2, bx2), iy2 = fminf(ay2, by2);
            float dx = fmaxf(__fsub_rn(ix2, ix1), 0.0f);
            float dy = fmaxf(__fsub_rn(iy2, iy1), 0.0f);
            float inter = __fmul_rn(dx, dy);
            float uni = __fsub_rn(__fadd_rn(areai, areaj), inter);
            float iou = __fdiv_rn(inter, fmaxf(uni, 1e-9f));
            if (iou > NMS_T) bits |= (1ull << bb);
        }
        mask[i * 16 + w] = bits;
    }
    __syncthreads();

    if (tid < 64) {
        int lane = tid;
        uint64_t rem = (lane < 16) ? removed_w[lane] : 0;
        for (int i = 0; i < TOPK_N; ++i) {
            uint64_t rw = __shfl(rem, i >> 6);
            bool alive = ((rw >> (i & 63)) & 1ull) == 0;
            uint64_t m = mask[i * 16 + (lane & 15)];
            if (alive && lane < 16) rem |= m;
        }
        if (lane < 16) removed_w[lane] = rem;
    }
    __syncthreads();

    for (int t = tid; t < TOPK_N; t += 1024) {
        bool kept = ((removed_w[t >> 6] >> (t & 63)) & 1ull) == 0;
        float* dr = dets + ((size_t)b * TOPK_N + t) * 6;
        if (kept) {
            dr[0] = lx1[t]; dr[1] = ly1[t]; dr[2] = lx2[t]; dr[3] = ly2[t];
            dr[4] = lsc[t]; dr[5] = lcl[t];
        } else {
            dr[0] = 0.0f; dr[1] = 0.0f; dr[2] = 0.0f;
            dr[3] = 0.0f; dr[4] = 0.0f; dr[5] = 0.0f;
        }
        keep_out[b * TOPK_N + t] = kept ? 1.0f : 0.0f;
    }
}

extern "C" void kernel_launch(void* const* d_in, const int* in_sizes, int n_in,
                              void* d_out, int out_size, void* d_ws, size_t ws_size,
                              hipStream_t stream) {
    const float* pred = (const float*)d_in[0];
    float* dets = (float*)d_out;                              // 32*1000*6
    float* keep = (float*)d_out + (size_t)NBATCH * TOPK_N * 6;

    const size_t total_rows = (size_t)NBATCH * NPRED;         // 268800
    const size_t keys_bytes = total_rows * sizeof(uint32_t);  // 1,075,200
    const size_t recs_bytes = total_rows * REC_F * sizeof(float); // 8,601,600

    if (ws_size >= keys_bytes + recs_bytes) {
        uint32_t* keys32 = (uint32_t*)d_ws;
        float* recs      = (float*)((char*)d_ws + keys_bytes);

        decode_kernel<<<(int)(total_rows / ROWS_PB), 256, 0, stream>>>(pred, keys32, recs);
        fused4_kernel<<<NBATCH, 1024, 0, stream>>>(keys32, recs, dets, keep);
    } else {
        int* top_idx = (int*)d_ws;
        topk_kernel<<<NBATCH, 1024, 0, stream>>>(pred, top_idx);
        nms_kernel<<<NBATCH, 1024, 0, stream>>>(pred, top_idx, dets, keep);
    }
}